// Round 1
// baseline (21350.449 us; speedup 1.0000x reference)
//
#include <hip/hip_runtime.h>
#include <math.h>
#include <cstddef>

// GPT-2 small forward: L=12 H=12 C=768 D=64 V=50257, B=2 T=1024 (M=2048 rows)
// Round 1: correctness-first fp32 vector implementation.
//   - tiled SGEMM (LDS-staged, float4 fragments, fused bias/GELU/residual)
//   - streaming causal attention, online softmax, one thread per q-row
//   - exact erf GELU, LN per row
// Next rounds: bf16 MFMA GEMMs, fused QKV, MFMA attention.

#define Cdim 768
#define Ddim 64
#define Hn   12
#define Ln   12
#define Tn   1024
#define Bn   2
#define Mrows (Bn * Tn)

__device__ __forceinline__ float gelu_f(float v) {
    return 0.5f * v * (1.0f + erff(v * 0.70710678118654752f));
}

// ---------------- embedding ----------------
__global__ void embed_k(const int* __restrict__ idx, const float* __restrict__ wte,
                        const float* __restrict__ wpe, float* __restrict__ x) {
    int i = blockIdx.x * 256 + threadIdx.x;           // over M*C
    int c  = i % Cdim;
    int bt = i / Cdim;
    int t  = bt % Tn;
    int tok = idx[bt];
    x[i] = wte[(size_t)tok * Cdim + c] + wpe[(size_t)t * Cdim + c];
}

// ---------------- layer norm (one block per row) ----------------
__global__ __launch_bounds__(256) void ln_k(const float* __restrict__ x,
                                            const float* __restrict__ w,
                                            const float* __restrict__ b,
                                            float* __restrict__ out) {
    int row = blockIdx.x;
    const float* xr = x + (size_t)row * Cdim;
    int t = threadIdx.x;
    float v0 = xr[t], v1 = xr[t + 256], v2 = xr[t + 512];
    float s = v0 + v1 + v2;
    #pragma unroll
    for (int o = 32; o > 0; o >>= 1) s += __shfl_xor(s, o);
    __shared__ float red[8];
    int wid = t >> 6;
    if ((t & 63) == 0) red[wid] = s;
    __syncthreads();
    float mean = (red[0] + red[1] + red[2] + red[3]) * (1.0f / 768.0f);
    float d0 = v0 - mean, d1 = v1 - mean, d2 = v2 - mean;
    float sq = d0 * d0 + d1 * d1 + d2 * d2;
    #pragma unroll
    for (int o = 32; o > 0; o >>= 1) sq += __shfl_xor(sq, o);
    if ((t & 63) == 0) red[4 + wid] = sq;
    __syncthreads();
    float var = (red[4] + red[5] + red[6] + red[7]) * (1.0f / 768.0f);
    float rstd = rsqrtf(var + 1e-5f);
    float* orow = out + (size_t)row * Cdim;
    orow[t]       = d0 * rstd * w[t]       + b[t];
    orow[t + 256] = d1 * rstd * w[t + 256] + b[t + 256];
    orow[t + 512] = d2 * rstd * w[t + 512] + b[t + 512];
}

// ---------------- tiled SGEMM: C = A[M,K] @ B[K,N] (+bias, +GELU, +residual) ----------------
template <int BM, int BN, int TM, int TN, bool BIAS, bool DO_GELU, bool RES>
__global__ __launch_bounds__(256) void gemm_k(const float* __restrict__ A,
                                              const float* __restrict__ Bw,
                                              const float* __restrict__ bias,
                                              const float* __restrict__ res,
                                              float* __restrict__ Cout,
                                              int M, int N, int K) {
    constexpr int BK = 16;
    __shared__ float As[BK][BM + 4];   // stored transposed: As[k][m]
    __shared__ float Bs[BK][BN + 4];
    const int tid = threadIdx.x;
    const int tx = tid % (BN / TN);
    const int ty = tid / (BN / TN);
    const int m0 = blockIdx.y * BM;
    const int n0 = blockIdx.x * BN;

    float acc[TM][TN];
    #pragma unroll
    for (int i = 0; i < TM; ++i)
        #pragma unroll
        for (int j = 0; j < TN; ++j) acc[i][j] = 0.0f;

    const bool nfast = ((n0 + BN) <= N) && ((N & 3) == 0);
    const int nkb = K / BK;
    for (int kb = 0; kb < nkb; ++kb) {
        const int k0 = kb * BK;
        __syncthreads();
        // stage A tile (transposed into LDS)
        for (int i = tid; i < BM * BK / 4; i += 256) {
            int r = i >> 2;          // BK/4 == 4 float4 per row
            int kq = i & 3;
            float4 av = *(const float4*)&A[(size_t)(m0 + r) * K + k0 + kq * 4];
            As[kq * 4 + 0][r] = av.x;
            As[kq * 4 + 1][r] = av.y;
            As[kq * 4 + 2][r] = av.z;
            As[kq * 4 + 3][r] = av.w;
        }
        // stage B tile
        if (nfast) {
            for (int i = tid; i < BK * BN / 4; i += 256) {
                int r = i / (BN / 4);
                int nf = i % (BN / 4);
                *(float4*)&Bs[r][nf * 4] =
                    *(const float4*)&Bw[(size_t)(k0 + r) * N + n0 + nf * 4];
            }
        } else {
            for (int i = tid; i < BK * BN; i += 256) {
                int r = i / BN, c = i % BN;
                int n = n0 + c;
                Bs[r][c] = (n < N) ? Bw[(size_t)(k0 + r) * N + n] : 0.0f;
            }
        }
        __syncthreads();
        #pragma unroll
        for (int kk = 0; kk < BK; ++kk) {
            float a[TM], b[TN];
            #pragma unroll
            for (int i = 0; i < TM; i += 4)
                *(float4*)&a[i] = *(const float4*)&As[kk][ty * TM + i];
            #pragma unroll
            for (int j = 0; j < TN; j += 4)
                *(float4*)&b[j] = *(const float4*)&Bs[kk][tx * TN + j];
            #pragma unroll
            for (int i = 0; i < TM; ++i)
                #pragma unroll
                for (int j = 0; j < TN; ++j)
                    acc[i][j] = fmaf(a[i], b[j], acc[i][j]);
        }
    }
    // epilogue
    #pragma unroll
    for (int i = 0; i < TM; ++i) {
        int row = m0 + ty * TM + i;
        #pragma unroll
        for (int j = 0; j < TN; ++j) {
            int col = n0 + tx * TN + j;
            if (col < N) {
                float vv = acc[i][j];
                if (BIAS) vv += bias[col];
                if (DO_GELU) vv = gelu_f(vv);
                if (RES) vv += res[(size_t)row * N + col];
                Cout[(size_t)row * N + col] = vv;
            }
        }
    }
}

// ---------------- causal attention, online softmax ----------------
// grid: (4 chunks of 256 q-rows, H, B); one thread per q-row.
__global__ __launch_bounds__(256, 1) void attn_k(const float* __restrict__ qb,
                                                 const float* __restrict__ kb,
                                                 const float* __restrict__ vb,
                                                 float* __restrict__ yb) {
    __shared__ float Ks[64][68];
    __shared__ float Vs[64][68];
    const int chunk = blockIdx.x, h = blockIdx.y, b = blockIdx.z;
    const int row = chunk * 256 + threadIdx.x;
    const float* qr = qb + ((size_t)(b * Tn + row) * Cdim + h * Ddim);
    float Q[64], O[64];
    #pragma unroll
    for (int d = 0; d < 64; ++d) { Q[d] = qr[d]; O[d] = 0.0f; }
    float mrun = -1e30f, lrun = 0.0f;
    const int nkt = (chunk + 1) * 4;
    for (int kt = 0; kt < nkt; ++kt) {
        __syncthreads();
        for (int i = threadIdx.x; i < 64 * 16; i += 256) {
            int r = i >> 4, cf = i & 15;
            size_t base = (size_t)(b * Tn + kt * 64 + r) * Cdim + h * Ddim + cf * 4;
            *(float4*)&Ks[r][cf * 4] = *(const float4*)&kb[base];
            *(float4*)&Vs[r][cf * 4] = *(const float4*)&vb[base];
        }
        __syncthreads();
        const int kmax = min(64, row - kt * 64 + 1);
        for (int kk = 0; kk < kmax; ++kk) {
            float s0 = 0, s1 = 0, s2 = 0, s3 = 0;
            #pragma unroll
            for (int d4 = 0; d4 < 16; ++d4) {
                float4 kv = *(const float4*)&Ks[kk][d4 * 4];
                s0 = fmaf(Q[d4 * 4 + 0], kv.x, s0);
                s1 = fmaf(Q[d4 * 4 + 1], kv.y, s1);
                s2 = fmaf(Q[d4 * 4 + 2], kv.z, s2);
                s3 = fmaf(Q[d4 * 4 + 3], kv.w, s3);
            }
            float s = ((s0 + s1) + (s2 + s3)) * 0.125f;
            if (s > mrun) {
                float corr = __expf(mrun - s);
                lrun = lrun * corr + 1.0f;
                #pragma unroll
                for (int d4 = 0; d4 < 16; ++d4) {
                    float4 vv = *(const float4*)&Vs[kk][d4 * 4];
                    O[d4 * 4 + 0] = fmaf(O[d4 * 4 + 0], corr, vv.x);
                    O[d4 * 4 + 1] = fmaf(O[d4 * 4 + 1], corr, vv.y);
                    O[d4 * 4 + 2] = fmaf(O[d4 * 4 + 2], corr, vv.z);
                    O[d4 * 4 + 3] = fmaf(O[d4 * 4 + 3], corr, vv.w);
                }
                mrun = s;
            } else {
                float p = __expf(s - mrun);
                lrun += p;
                #pragma unroll
                for (int d4 = 0; d4 < 16; ++d4) {
                    float4 vv = *(const float4*)&Vs[kk][d4 * 4];
                    O[d4 * 4 + 0] = fmaf(p, vv.x, O[d4 * 4 + 0]);
                    O[d4 * 4 + 1] = fmaf(p, vv.y, O[d4 * 4 + 1]);
                    O[d4 * 4 + 2] = fmaf(p, vv.z, O[d4 * 4 + 2]);
                    O[d4 * 4 + 3] = fmaf(p, vv.w, O[d4 * 4 + 3]);
                }
            }
        }
    }
    float inv = 1.0f / lrun;
    float* yr = yb + ((size_t)(b * Tn + row) * Cdim + h * Ddim);
    #pragma unroll
    for (int d = 0; d < 64; ++d) yr[d] = O[d] * inv;
}

extern "C" void kernel_launch(void* const* d_in, const int* in_sizes, int n_in,
                              void* d_out, int out_size, void* d_ws, size_t ws_size,
                              hipStream_t stream) {
    const int*   idx  = (const int*)d_in[0];
    const float* wte  = (const float*)d_in[1];
    const float* wpe  = (const float*)d_in[2];
    const float* ln1w = (const float*)d_in[3];
    const float* ln1b = (const float*)d_in[4];
    const float* Wq   = (const float*)d_in[5];
    const float* bq   = (const float*)d_in[6];
    const float* Wk   = (const float*)d_in[7];
    const float* bk   = (const float*)d_in[8];
    const float* Wv   = (const float*)d_in[9];
    const float* bv   = (const float*)d_in[10];
    const float* Wo   = (const float*)d_in[11];
    const float* bo   = (const float*)d_in[12];
    const float* ln2w = (const float*)d_in[13];
    const float* ln2b = (const float*)d_in[14];
    const float* Wfc  = (const float*)d_in[15];
    const float* bfc  = (const float*)d_in[16];
    const float* Wpr  = (const float*)d_in[17];
    const float* bpr  = (const float*)d_in[18];
    const float* lnfw = (const float*)d_in[19];
    const float* lnfb = (const float*)d_in[20];
    const float* Wlm  = (const float*)d_in[21];
    float* out = (float*)d_out;

    const int M = Mrows;                     // 2048
    const int V = out_size / M;              // 50257

    // workspace layout (fp32)
    float* x   = (float*)d_ws;               // M*C residual stream
    float* hb  = x   + (size_t)M * Cdim;     // M*C  LN output
    float* qb  = hb  + (size_t)M * Cdim;
    float* kb  = qb  + (size_t)M * Cdim;
    float* vb  = kb  + (size_t)M * Cdim;
    float* yb  = vb  + (size_t)M * Cdim;
    float* mid = yb  + (size_t)M * Cdim;     // M*4C

    embed_k<<<(M * Cdim) / 256, 256, 0, stream>>>(idx, wte, wpe, x);

    for (int l = 0; l < Ln; ++l) {
        const size_t wo2 = (size_t)l * Cdim * Cdim;
        const size_t wo4 = (size_t)l * Cdim * 4 * Cdim;
        ln_k<<<M, 256, 0, stream>>>(x, ln1w + l * Cdim, ln1b + l * Cdim, hb);
        gemm_k<128, 64, 8, 4, true, false, false><<<dim3(12, 16), 256, 0, stream>>>(
            hb, Wq + wo2, bq + l * Cdim, nullptr, qb, M, Cdim, Cdim);
        gemm_k<128, 64, 8, 4, true, false, false><<<dim3(12, 16), 256, 0, stream>>>(
            hb, Wk + wo2, bk + l * Cdim, nullptr, kb, M, Cdim, Cdim);
        gemm_k<128, 64, 8, 4, true, false, false><<<dim3(12, 16), 256, 0, stream>>>(
            hb, Wv + wo2, bv + l * Cdim, nullptr, vb, M, Cdim, Cdim);
        attn_k<<<dim3(4, Hn, Bn), 256, 0, stream>>>(qb, kb, vb, yb);
        gemm_k<128, 64, 8, 4, true, false, true><<<dim3(12, 16), 256, 0, stream>>>(
            yb, Wo + wo2, bo + l * Cdim, x, x, M, Cdim, Cdim);
        ln_k<<<M, 256, 0, stream>>>(x, ln2w + l * Cdim, ln2b + l * Cdim, hb);
        gemm_k<128, 128, 8, 8, true, true, false><<<dim3(24, 16), 256, 0, stream>>>(
            hb, Wfc + wo4, bfc + l * 4 * Cdim, nullptr, mid, M, 4 * Cdim, Cdim);
        gemm_k<128, 64, 8, 4, true, false, true><<<dim3(12, 16), 256, 0, stream>>>(
            mid, Wpr + wo4, bpr + l * Cdim, x, x, M, Cdim, 4 * Cdim);
    }

    ln_k<<<M, 256, 0, stream>>>(x, lnfw, lnfb, hb);
    const int ntiles = (V + 127) / 128;      // 393
    gemm_k<128, 128, 8, 8, false, false, false><<<dim3(ntiles, 16), 256, 0, stream>>>(
        hb, Wlm, nullptr, nullptr, out, M, V, Cdim);
}

// Round 2
// 10154.451 us; speedup vs baseline: 2.1026x; 2.1026x over previous
//
#include <hip/hip_runtime.h>
#include <math.h>
#include <cstddef>

// GPT-2 small forward: L=12 H=12 C=768 D=64 V=50257, B=2 T=1024 (M=2048)
// Round 2: bf16 MFMA GEMMs (m97 structure: 128x128 tile, BK=32, global_load_lds,
// W^T bf16 staged per layer in ws), fused QKV (N=2304), fused bias/GELU/residual
// epilogues. Attention still fp32 thread-per-row (next target).

#define Cdim 768
#define Hn   12
#define Ln   12
#define Tn   1024
#define Bn   2
#define Mrows (Bn * Tn)

typedef unsigned short ushort_t;
typedef __bf16 bf16x8 __attribute__((ext_vector_type(8)));
typedef float  f32x4  __attribute__((ext_vector_type(4)));

__device__ __forceinline__ ushort_t f2bf(float v) {
    union { float f; unsigned int u; } x; x.f = v;
    unsigned int r = x.u + 0x7fffu + ((x.u >> 16) & 1u);   // round-nearest-even
    return (ushort_t)(r >> 16);
}
__device__ __forceinline__ float gelu_f(float v) {
    return 0.5f * v * (1.0f + erff(v * 0.70710678118654752f));
}
__device__ __forceinline__ void gload16(const void* g, void* l) {
    __builtin_amdgcn_global_load_lds(
        (const __attribute__((address_space(1))) unsigned int*)g,
        (__attribute__((address_space(3))) unsigned int*)l, 16, 0, 0);
}

// ---------------- embedding ----------------
__global__ void embed_k(const int* __restrict__ idx, const float* __restrict__ wte,
                        const float* __restrict__ wpe, float* __restrict__ x) {
    int i = blockIdx.x * 256 + threadIdx.x;           // over M*C
    int c  = i % Cdim;
    int bt = i / Cdim;
    int t  = bt % Tn;
    int tok = idx[bt];
    x[i] = wte[(size_t)tok * Cdim + c] + wpe[(size_t)t * Cdim + c];
}

// ---------------- layer norm -> bf16 (one block per row) ----------------
__global__ __launch_bounds__(256) void ln_k(const float* __restrict__ x,
                                            const float* __restrict__ w,
                                            const float* __restrict__ b,
                                            ushort_t* __restrict__ out) {
    int row = blockIdx.x;
    const float* xr = x + (size_t)row * Cdim;
    int t = threadIdx.x;
    float v0 = xr[t], v1 = xr[t + 256], v2 = xr[t + 512];
    float s = v0 + v1 + v2;
    #pragma unroll
    for (int o = 32; o > 0; o >>= 1) s += __shfl_xor(s, o);
    __shared__ float red[8];
    int wid = t >> 6;
    if ((t & 63) == 0) red[wid] = s;
    __syncthreads();
    float mean = (red[0] + red[1] + red[2] + red[3]) * (1.0f / 768.0f);
    float d0 = v0 - mean, d1 = v1 - mean, d2 = v2 - mean;
    float sq = d0 * d0 + d1 * d1 + d2 * d2;
    #pragma unroll
    for (int o = 32; o > 0; o >>= 1) sq += __shfl_xor(sq, o);
    if ((t & 63) == 0) red[4 + wid] = sq;
    __syncthreads();
    float var = (red[4] + red[5] + red[6] + red[7]) * (1.0f / 768.0f);
    float rstd = rsqrtf(var + 1e-5f);
    ushort_t* orow = out + (size_t)row * Cdim;
    orow[t]       = f2bf(d0 * rstd * w[t]       + b[t]);
    orow[t + 256] = f2bf(d1 * rstd * w[t + 256] + b[t + 256]);
    orow[t + 512] = f2bf(d2 * rstd * w[t + 512] + b[t + 512]);
}

// ---------------- weight transpose + fp32->bf16: W[K][N] -> WT[Npad][K] ----------------
// grid: (Npad/32, K/32), 256 threads. Rows n >= N are zero-padded.
__global__ __launch_bounds__(256) void wconv_k(const float* __restrict__ W,
                                               ushort_t* __restrict__ WT,
                                               int K, int N) {
    __shared__ float t[32][33];
    int x = threadIdx.x & 31, y = threadIdx.x >> 5;    // y in 0..7
    int n0 = blockIdx.x * 32, k0 = blockIdx.y * 32;
    #pragma unroll
    for (int j = 0; j < 4; ++j) {
        int kk = k0 + y + j * 8, nn = n0 + x;
        t[y + j * 8][x] = (nn < N) ? W[(size_t)kk * N + nn] : 0.0f;
    }
    __syncthreads();
    #pragma unroll
    for (int j = 0; j < 4; ++j) {
        int nn = n0 + y + j * 8, kk = k0 + x;
        WT[(size_t)nn * K + kk] = f2bf(t[x][y + j * 8]);
    }
}

// ---------------- pack qkv biases ----------------
__global__ void packb_k(const float* __restrict__ bq, const float* __restrict__ bk,
                        const float* __restrict__ bv, float* __restrict__ bqkv) {
    int i = blockIdx.x * 256 + threadIdx.x;   // 2304
    bqkv[i] = (i < 768) ? bq[i] : (i < 1536 ? bk[i - 768] : bv[i - 1536]);
}

// ---------------- bf16 MFMA GEMM: C = A[M,K] @ Bt[N,K]^T (+bias,+GELU,+res) ----------------
// 128x128 tile, BK=32, 256 threads = 4 waves (2x2), each wave 64x64 out.
template <bool BIAS, bool GELU_, bool RES, bool OUTBF16>
__global__ __launch_bounds__(256) void gemm_bf16_k(
    const ushort_t* __restrict__ A,    // [M][K] bf16
    const ushort_t* __restrict__ Bt,   // [Npad][K] bf16 (weights transposed)
    const float* __restrict__ bias,
    const float* __restrict__ res,     // [M][N] fp32
    void* __restrict__ Cout,
    int M, int N, int K) {
    __shared__ ushort_t Alds[128 * 32];
    __shared__ ushort_t Blds[128 * 32];
    const int tid = threadIdx.x;
    const int lane = tid & 63;
    const int w = tid >> 6;
    const int wr = w >> 1, wc = w & 1;
    const int m0 = blockIdx.y * 128;
    const int n0 = blockIdx.x * 128;

    f32x4 acc[4][4] = {};

    // staging: wave w covers tile rows [w*32, w*32+32); per issue 16 rows.
    const int srow = w * 32 + (lane >> 2);
    const int skoff = (lane & 3) * 8;
    const ushort_t* Ab = A  + (size_t)(m0 + srow) * K + skoff;
    const ushort_t* Bb = Bt + (size_t)(n0 + srow) * K + skoff;
    char* Al = (char*)Alds + (w * 2048 + lane * 16);
    char* Bl = (char*)Blds + (w * 2048 + lane * 16);

    const int nk = K >> 5;
    for (int kb = 0; kb < nk; ++kb) {
        const int k0 = kb << 5;
        __syncthreads();                       // readers of prev tile done
        gload16(Ab + k0,                 Al);
        gload16(Ab + k0 + (size_t)16 * K, Al + 1024);
        gload16(Bb + k0,                 Bl);
        gload16(Bb + k0 + (size_t)16 * K, Bl + 1024);
        __syncthreads();                       // compiler drains vmcnt(0) before barrier
        bf16x8 af[4], bfr[4];
        #pragma unroll
        for (int i = 0; i < 4; ++i) {
            af[i]  = *(const bf16x8*)((const char*)Alds +
                       ((wr * 64 + i * 16 + (lane & 15)) * 64 + (lane >> 4) * 16));
            bfr[i] = *(const bf16x8*)((const char*)Blds +
                       ((wc * 64 + i * 16 + (lane & 15)) * 64 + (lane >> 4) * 16));
        }
        #pragma unroll
        for (int mi = 0; mi < 4; ++mi)
            #pragma unroll
            for (int ni = 0; ni < 4; ++ni)
                acc[mi][ni] = __builtin_amdgcn_mfma_f32_16x16x32_bf16(
                    af[mi], bfr[ni], acc[mi][ni], 0, 0, 0);
    }

    // epilogue: C/D layout col=lane&15, row=(lane>>4)*4+q
    const int r0 = (lane >> 4) * 4;
    const int c0 = lane & 15;
    #pragma unroll
    for (int mi = 0; mi < 4; ++mi) {
        #pragma unroll
        for (int ni = 0; ni < 4; ++ni) {
            int col = n0 + wc * 64 + ni * 16 + c0;
            if (col < N) {
                #pragma unroll
                for (int q = 0; q < 4; ++q) {
                    int row = m0 + wr * 64 + mi * 16 + r0 + q;
                    float v = acc[mi][ni][q];
                    if (BIAS) v += bias[col];
                    if (GELU_) v = gelu_f(v);
                    if (RES) v += res[(size_t)row * N + col];
                    if (OUTBF16) ((ushort_t*)Cout)[(size_t)row * N + col] = f2bf(v);
                    else         ((float*)Cout)[(size_t)row * N + col] = v;
                }
            }
        }
    }
}

// ---------------- causal attention, online softmax (fp32, fused-qkv input) ----------------
// grid: (4 chunks of 256 q-rows, H, B); one thread per q-row. qkv stride 2304.
__global__ __launch_bounds__(256, 1) void attn_k(const float* __restrict__ qkv,
                                                 ushort_t* __restrict__ yb) {
    __shared__ float Ks[64][68];
    __shared__ float Vs[64][68];
    const int chunk = blockIdx.x, h = blockIdx.y, b = blockIdx.z;
    const int row = chunk * 256 + threadIdx.x;
    const float* qr = qkv + (size_t)(b * Tn + row) * 2304 + h * 64;
    float Q[64], O[64];
    #pragma unroll
    for (int d = 0; d < 64; ++d) { Q[d] = qr[d]; O[d] = 0.0f; }
    float mrun = -1e30f, lrun = 0.0f;
    const int nkt = (chunk + 1) * 4;
    for (int kt = 0; kt < nkt; ++kt) {
        __syncthreads();
        for (int i = threadIdx.x; i < 64 * 16; i += 256) {
            int r = i >> 4, cf = i & 15;
            size_t base = (size_t)(b * Tn + kt * 64 + r) * 2304 + h * 64 + cf * 4;
            *(float4*)&Ks[r][cf * 4] = *(const float4*)&qkv[base + 768];
            *(float4*)&Vs[r][cf * 4] = *(const float4*)&qkv[base + 1536];
        }
        __syncthreads();
        const int kmax = min(64, row - kt * 64 + 1);
        for (int kk = 0; kk < kmax; ++kk) {
            float s0 = 0, s1 = 0, s2 = 0, s3 = 0;
            #pragma unroll
            for (int d4 = 0; d4 < 16; ++d4) {
                float4 kv = *(const float4*)&Ks[kk][d4 * 4];
                s0 = fmaf(Q[d4 * 4 + 0], kv.x, s0);
                s1 = fmaf(Q[d4 * 4 + 1], kv.y, s1);
                s2 = fmaf(Q[d4 * 4 + 2], kv.z, s2);
                s3 = fmaf(Q[d4 * 4 + 3], kv.w, s3);
            }
            float s = ((s0 + s1) + (s2 + s3)) * 0.125f;
            if (s > mrun) {
                float corr = __expf(mrun - s);
                lrun = lrun * corr + 1.0f;
                #pragma unroll
                for (int d4 = 0; d4 < 16; ++d4) {
                    float4 vv = *(const float4*)&Vs[kk][d4 * 4];
                    O[d4 * 4 + 0] = fmaf(O[d4 * 4 + 0], corr, vv.x);
                    O[d4 * 4 + 1] = fmaf(O[d4 * 4 + 1], corr, vv.y);
                    O[d4 * 4 + 2] = fmaf(O[d4 * 4 + 2], corr, vv.z);
                    O[d4 * 4 + 3] = fmaf(O[d4 * 4 + 3], corr, vv.w);
                }
                mrun = s;
            } else {
                float p = __expf(s - mrun);
                lrun += p;
                #pragma unroll
                for (int d4 = 0; d4 < 16; ++d4) {
                    float4 vv = *(const float4*)&Vs[kk][d4 * 4];
                    O[d4 * 4 + 0] = fmaf(p, vv.x, O[d4 * 4 + 0]);
                    O[d4 * 4 + 1] = fmaf(p, vv.y, O[d4 * 4 + 1]);
                    O[d4 * 4 + 2] = fmaf(p, vv.z, O[d4 * 4 + 2]);
                    O[d4 * 4 + 3] = fmaf(p, vv.w, O[d4 * 4 + 3]);
                }
            }
        }
    }
    float inv = 1.0f / lrun;
    ushort_t* yr = yb + (size_t)(b * Tn + row) * Cdim + h * 64;
    #pragma unroll
    for (int d = 0; d < 64; ++d) yr[d] = f2bf(O[d] * inv);
}

extern "C" void kernel_launch(void* const* d_in, const int* in_sizes, int n_in,
                              void* d_out, int out_size, void* d_ws, size_t ws_size,
                              hipStream_t stream) {
    const int*   idx  = (const int*)d_in[0];
    const float* wte  = (const float*)d_in[1];
    const float* wpe  = (const float*)d_in[2];
    const float* ln1w = (const float*)d_in[3];
    const float* ln1b = (const float*)d_in[4];
    const float* Wq   = (const float*)d_in[5];
    const float* bq   = (const float*)d_in[6];
    const float* Wk   = (const float*)d_in[7];
    const float* bk   = (const float*)d_in[8];
    const float* Wv   = (const float*)d_in[9];
    const float* bv   = (const float*)d_in[10];
    const float* Wo   = (const float*)d_in[11];
    const float* bo   = (const float*)d_in[12];
    const float* ln2w = (const float*)d_in[13];
    const float* ln2b = (const float*)d_in[14];
    const float* Wfc  = (const float*)d_in[15];
    const float* bfc  = (const float*)d_in[16];
    const float* Wpr  = (const float*)d_in[17];
    const float* bpr  = (const float*)d_in[18];
    const float* lnfw = (const float*)d_in[19];
    const float* lnfb = (const float*)d_in[20];
    const float* Wlm  = (const float*)d_in[21];
    float* out = (float*)d_out;

    const int M = Mrows;                     // 2048
    const int V = out_size / M;              // 50257
    const int Vpad = ((V + 127) / 128) * 128; // 50304

    // workspace layout
    float*    x     = (float*)d_ws;                       // M*C fp32 residual
    float*    qkv   = x + (size_t)M * Cdim;               // M*2304 fp32
    float*    bqkv  = qkv + (size_t)M * 2304;             // 2304 fp32
    ushort_t* hb    = (ushort_t*)(bqkv + 2304);           // M*C bf16 (LN out)
    ushort_t* yb    = hb + (size_t)M * Cdim;              // M*C bf16 (attn out)
    ushort_t* mid   = yb + (size_t)M * Cdim;              // M*4C bf16
    ushort_t* wqkvt = mid + (size_t)M * 4 * Cdim;         // [2304][768]
    ushort_t* wot   = wqkvt + (size_t)2304 * Cdim;        // [768][768]
    ushort_t* wfct  = wot + (size_t)Cdim * Cdim;          // [3072][768]
    ushort_t* wprt  = wfct + (size_t)3072 * Cdim;         // [768][3072]
    ushort_t* wlmt  = wprt + (size_t)Cdim * 3072;         // [Vpad][768]

    embed_k<<<(M * Cdim) / 256, 256, 0, stream>>>(idx, wte, wpe, x);

    for (int l = 0; l < Ln; ++l) {
        const size_t wo2 = (size_t)l * Cdim * Cdim;
        const size_t wo4 = (size_t)l * Cdim * 4 * Cdim;
        // convert this layer's weights -> transposed bf16
        wconv_k<<<dim3(24, 24), 256, 0, stream>>>(Wq + wo2, wqkvt,              Cdim, Cdim);
        wconv_k<<<dim3(24, 24), 256, 0, stream>>>(Wk + wo2, wqkvt + 768 * 768,  Cdim, Cdim);
        wconv_k<<<dim3(24, 24), 256, 0, stream>>>(Wv + wo2, wqkvt + 1536 * 768, Cdim, Cdim);
        wconv_k<<<dim3(24, 24), 256, 0, stream>>>(Wo + wo2, wot,  Cdim, Cdim);
        wconv_k<<<dim3(96, 24), 256, 0, stream>>>(Wfc + wo4, wfct, Cdim, 3072);
        wconv_k<<<dim3(24, 96), 256, 0, stream>>>(Wpr + wo4, wprt, 3072, Cdim);
        packb_k<<<9, 256, 0, stream>>>(bq + l * Cdim, bk + l * Cdim, bv + l * Cdim, bqkv);

        ln_k<<<M, 256, 0, stream>>>(x, ln1w + l * Cdim, ln1b + l * Cdim, hb);
        gemm_bf16_k<true, false, false, false><<<dim3(18, 16), 256, 0, stream>>>(
            hb, wqkvt, bqkv, nullptr, qkv, M, 2304, Cdim);
        attn_k<<<dim3(4, Hn, Bn), 256, 0, stream>>>(qkv, yb);
        gemm_bf16_k<true, false, true, false><<<dim3(6, 16), 256, 0, stream>>>(
            yb, wot, bo + l * Cdim, x, x, M, Cdim, Cdim);
        ln_k<<<M, 256, 0, stream>>>(x, ln2w + l * Cdim, ln2b + l * Cdim, hb);
        gemm_bf16_k<true, true, false, true><<<dim3(24, 16), 256, 0, stream>>>(
            hb, wfct, bfc + (size_t)l * 4 * Cdim, nullptr, mid, M, 3072, Cdim);
        gemm_bf16_k<true, false, true, false><<<dim3(6, 16), 256, 0, stream>>>(
            mid, wprt, bpr + l * Cdim, x, x, M, Cdim, 3072);
    }

    ln_k<<<M, 256, 0, stream>>>(x, lnfw, lnfb, hb);
    wconv_k<<<dim3(Vpad / 32, 24), 256, 0, stream>>>(Wlm, wlmt, Cdim, V);
    gemm_bf16_k<false, false, false, false><<<dim3(Vpad / 128, 16), 256, 0, stream>>>(
        hb, wlmt, nullptr, nullptr, out, M, V, Cdim);
}

// Round 3
// 2975.515 us; speedup vs baseline: 7.1754x; 3.4127x over previous
//
#include <hip/hip_runtime.h>
#include <math.h>
#include <cstddef>

// GPT-2 small forward: L=12 H=12 C=768 D=64 V=50257, B=2 T=1024 (M=2048)
// Round 3: MFMA flash attention (4 waves x 16 q-rows, KVB=64, padded-LDS bf16
// tiles, online softmax via 16-lane shfl reduce, P through wave-private LDS),
// QKV GEMM writes bf16, per-layer V-transpose kernel, merged weight-conv.

#define Cdim 768
#define Hn   12
#define Ln   12
#define Tn   1024
#define Bn   2
#define Mrows (Bn * Tn)

typedef unsigned short ushort_t;
typedef __bf16 bf16x8 __attribute__((ext_vector_type(8)));
typedef float  f32x4  __attribute__((ext_vector_type(4)));

__device__ __forceinline__ ushort_t f2bf(float v) {
    union { float f; unsigned int u; } x; x.f = v;
    unsigned int r = x.u + 0x7fffu + ((x.u >> 16) & 1u);   // RNE
    return (ushort_t)(r >> 16);
}
__device__ __forceinline__ float gelu_f(float v) {
    return 0.5f * v * (1.0f + erff(v * 0.70710678118654752f));
}
__device__ __forceinline__ void gload16(const void* g, void* l) {
    __builtin_amdgcn_global_load_lds(
        (const __attribute__((address_space(1))) unsigned int*)g,
        (__attribute__((address_space(3))) unsigned int*)l, 16, 0, 0);
}

// ---------------- embedding ----------------
__global__ void embed_k(const int* __restrict__ idx, const float* __restrict__ wte,
                        const float* __restrict__ wpe, float* __restrict__ x) {
    int i = blockIdx.x * 256 + threadIdx.x;
    int c  = i % Cdim;
    int bt = i / Cdim;
    int t  = bt % Tn;
    int tok = idx[bt];
    x[i] = wte[(size_t)tok * Cdim + c] + wpe[(size_t)t * Cdim + c];
}

// ---------------- layer norm -> bf16 ----------------
__global__ __launch_bounds__(256) void ln_k(const float* __restrict__ x,
                                            const float* __restrict__ w,
                                            const float* __restrict__ b,
                                            ushort_t* __restrict__ out) {
    int row = blockIdx.x;
    const float* xr = x + (size_t)row * Cdim;
    int t = threadIdx.x;
    float v0 = xr[t], v1 = xr[t + 256], v2 = xr[t + 512];
    float s = v0 + v1 + v2;
    #pragma unroll
    for (int o = 32; o > 0; o >>= 1) s += __shfl_xor(s, o);
    __shared__ float red[8];
    int wid = t >> 6;
    if ((t & 63) == 0) red[wid] = s;
    __syncthreads();
    float mean = (red[0] + red[1] + red[2] + red[3]) * (1.0f / 768.0f);
    float d0 = v0 - mean, d1 = v1 - mean, d2 = v2 - mean;
    float sq = d0 * d0 + d1 * d1 + d2 * d2;
    #pragma unroll
    for (int o = 32; o > 0; o >>= 1) sq += __shfl_xor(sq, o);
    if ((t & 63) == 0) red[4 + wid] = sq;
    __syncthreads();
    float var = (red[4] + red[5] + red[6] + red[7]) * (1.0f / 768.0f);
    float rstd = rsqrtf(var + 1e-5f);
    ushort_t* orow = out + (size_t)row * Cdim;
    orow[t]       = f2bf(d0 * rstd * w[t]       + b[t]);
    orow[t + 256] = f2bf(d1 * rstd * w[t + 256] + b[t + 256]);
    orow[t + 512] = f2bf(d2 * rstd * w[t + 512] + b[t + 512]);
}

// ---------------- 32x32 transpose+cast tile helper ----------------
__device__ __forceinline__ void tconv_tile(const float* __restrict__ W,
                                           ushort_t* __restrict__ WT,
                                           int K, int N, int n0, int k0, bool guard) {
    __shared__ float t[32][33];
    int x = threadIdx.x & 31, y = threadIdx.x >> 5;
    #pragma unroll
    for (int j = 0; j < 4; ++j) {
        int kk = k0 + y + j * 8, nn = n0 + x;
        t[y + j * 8][x] = (!guard || nn < N) ? W[(size_t)kk * N + nn] : 0.0f;
    }
    __syncthreads();
    #pragma unroll
    for (int j = 0; j < 4; ++j) {
        int nn = n0 + y + j * 8, kk = k0 + x;
        WT[(size_t)nn * K + kk] = f2bf(t[x][y + j * 8]);
    }
}

// LM head (needs N guard/pad)
__global__ __launch_bounds__(256) void wconv_k(const float* __restrict__ W,
                                               ushort_t* __restrict__ WT,
                                               int K, int N) {
    tconv_tile(W, WT, K, N, blockIdx.x * 32, blockIdx.y * 32, true);
}

// four 768x768 (q,k,v,o), grid (24,24,4)
__global__ __launch_bounds__(256) void conv4_k(const float* __restrict__ Wq,
                                               const float* __restrict__ Wk,
                                               const float* __restrict__ Wv,
                                               const float* __restrict__ Wo,
                                               ushort_t* __restrict__ wqkvt,
                                               ushort_t* __restrict__ wot) {
    int z = blockIdx.z;
    const float* W = (z == 0) ? Wq : (z == 1) ? Wk : (z == 2) ? Wv : Wo;
    ushort_t* dst = (z < 3) ? (wqkvt + (size_t)z * 768 * 768) : wot;
    tconv_tile(W, dst, 768, 768, blockIdx.x * 32, blockIdx.y * 32, false);
}

// fc (768->3072) and pr (3072->768), grid (2304,1,2) flat
__global__ __launch_bounds__(256) void conv2_k(const float* __restrict__ Wfc,
                                               const float* __restrict__ Wpr,
                                               ushort_t* __restrict__ wfct,
                                               ushort_t* __restrict__ wprt) {
    int z = blockIdx.z;
    const float* W = z ? Wpr : Wfc;
    ushort_t* dst  = z ? wprt : wfct;
    int K = z ? 3072 : 768, N = z ? 768 : 3072;
    int nt = N / 32;
    int bx = blockIdx.x % nt, by = blockIdx.x / nt;
    tconv_tile(W, dst, K, N, bx * 32, by * 32, false);
}

// ---------------- pack qkv biases ----------------
__global__ void packb_k(const float* __restrict__ bq, const float* __restrict__ bk,
                        const float* __restrict__ bv, float* __restrict__ bqkv) {
    int i = blockIdx.x * 256 + threadIdx.x;
    bqkv[i] = (i < 768) ? bq[i] : (i < 1536 ? bk[i - 768] : bv[i - 1536]);
}

// ---------------- bf16 MFMA GEMM (m97 structure) ----------------
template <bool BIAS, bool GELU_, bool RES, bool OUTBF16>
__global__ __launch_bounds__(256) void gemm_bf16_k(
    const ushort_t* __restrict__ A, const ushort_t* __restrict__ Bt,
    const float* __restrict__ bias, const float* __restrict__ res,
    void* __restrict__ Cout, int M, int N, int K) {
    __shared__ ushort_t Alds[128 * 32];
    __shared__ ushort_t Blds[128 * 32];
    const int tid = threadIdx.x;
    const int lane = tid & 63;
    const int w = tid >> 6;
    const int wr = w >> 1, wc = w & 1;
    const int m0 = blockIdx.y * 128;
    const int n0 = blockIdx.x * 128;

    f32x4 acc[4][4] = {};
    const int srow = w * 32 + (lane >> 2);
    const int skoff = (lane & 3) * 8;
    const ushort_t* Ab = A  + (size_t)(m0 + srow) * K + skoff;
    const ushort_t* Bb = Bt + (size_t)(n0 + srow) * K + skoff;
    char* Al = (char*)Alds + (w * 2048 + lane * 16);
    char* Bl = (char*)Blds + (w * 2048 + lane * 16);

    const int nk = K >> 5;
    for (int kb = 0; kb < nk; ++kb) {
        const int k0 = kb << 5;
        __syncthreads();
        gload16(Ab + k0,                  Al);
        gload16(Ab + k0 + (size_t)16 * K, Al + 1024);
        gload16(Bb + k0,                  Bl);
        gload16(Bb + k0 + (size_t)16 * K, Bl + 1024);
        __syncthreads();
        bf16x8 af[4], bfr[4];
        #pragma unroll
        for (int i = 0; i < 4; ++i) {
            af[i]  = *(const bf16x8*)((const char*)Alds +
                       ((wr * 64 + i * 16 + (lane & 15)) * 64 + (lane >> 4) * 16));
            bfr[i] = *(const bf16x8*)((const char*)Blds +
                       ((wc * 64 + i * 16 + (lane & 15)) * 64 + (lane >> 4) * 16));
        }
        #pragma unroll
        for (int mi = 0; mi < 4; ++mi)
            #pragma unroll
            for (int ni = 0; ni < 4; ++ni)
                acc[mi][ni] = __builtin_amdgcn_mfma_f32_16x16x32_bf16(
                    af[mi], bfr[ni], acc[mi][ni], 0, 0, 0);
    }
    const int r0 = (lane >> 4) * 4;
    const int c0 = lane & 15;
    #pragma unroll
    for (int mi = 0; mi < 4; ++mi) {
        #pragma unroll
        for (int ni = 0; ni < 4; ++ni) {
            int col = n0 + wc * 64 + ni * 16 + c0;
            if (col < N) {
                #pragma unroll
                for (int q = 0; q < 4; ++q) {
                    int row = m0 + wr * 64 + mi * 16 + r0 + q;
                    float v = acc[mi][ni][q];
                    if (BIAS) v += bias[col];
                    if (GELU_) v = gelu_f(v);
                    if (RES) v += res[(size_t)row * N + col];
                    if (OUTBF16) ((ushort_t*)Cout)[(size_t)row * N + col] = f2bf(v);
                    else         ((float*)Cout)[(size_t)row * N + col] = v;
                }
            }
        }
    }
}

// ---------------- per-layer V transpose: qkvb V cols -> vtb[bh][64][Tn] ----------------
__global__ __launch_bounds__(256) void vtrans_k(const ushort_t* __restrict__ qkvb,
                                                ushort_t* __restrict__ vtb) {
    __shared__ ushort_t Ls[256][72];
    const int tc = blockIdx.x, h = blockIdx.y, b = blockIdx.z;
    const int tid = threadIdx.x;
    const ushort_t* src = qkvb + (size_t)(b * Tn + tc * 256 + tid) * 2304 + 1536 + h * 64;
    #pragma unroll
    for (int i = 0; i < 8; ++i)
        *(uint4*)&Ls[tid][i * 8] = *(const uint4*)(src + i * 8);
    __syncthreads();
    const int d = tid & 63, tg = tid >> 6;
    ushort_t tmp[64];
    #pragma unroll
    for (int i = 0; i < 64; ++i) tmp[i] = Ls[tg * 64 + i][d];
    ushort_t* dst = vtb + ((size_t)(b * Hn + h) * 64 + d) * Tn + tc * 256 + tg * 64;
    #pragma unroll
    for (int i = 0; i < 8; ++i)
        *(uint4*)&dst[i * 8] = *(const uint4*)&tmp[i * 8];
}

// ---------------- MFMA flash attention ----------------
// grid (16, H, B), 256 thr = 4 waves; wave owns 16 q-rows; KV tiles of 64.
__global__ __launch_bounds__(256) void attn_mfma_k(
    const ushort_t* __restrict__ qkvb,   // [M][2304] bf16
    const ushort_t* __restrict__ vtb,    // [B*H][64][Tn] bf16
    ushort_t* __restrict__ yb) {         // [M][768] bf16
    __shared__ ushort_t Ks[64][72];
    __shared__ ushort_t Vt[64][72];
    __shared__ ushort_t Pl[4][16][72];
    const int chunk = (Tn / 64 - 1) - blockIdx.x;   // heavy blocks first
    const int h = blockIdx.y, b = blockIdx.z;
    const int tid = threadIdx.x, lane = tid & 63, w = tid >> 6;
    const int c = lane & 15, g = lane >> 4;
    const int qrow0 = chunk * 64 + w * 16;

    const ushort_t* qp = qkvb + (size_t)(b * Tn + qrow0 + c) * 2304 + h * 64 + g * 8;
    bf16x8 qa0 = *(const bf16x8*)qp;
    bf16x8 qa1 = *(const bf16x8*)(qp + 32);

    f32x4 accO[4] = {};
    float mrun[4], lrun[4];
    #pragma unroll
    for (int q = 0; q < 4; ++q) { mrun[q] = -1e30f; lrun[q] = 0.0f; }

    const int skey = tid >> 2, sd0 = (tid & 3) * 16;
    const ushort_t* ksrc = qkvb + (size_t)(b * Tn + skey) * 2304 + 768 + h * 64 + sd0;
    const int vd = tid >> 2, vseg = tid & 3;
    const ushort_t* vsrc = vtb + ((size_t)(b * Hn + h) * 64 + vd) * Tn + vseg * 16;
    ushort_t* KsW = &Ks[skey][sd0];
    ushort_t* VtW = &Vt[vd][vseg * 16];

    const int ntiles = chunk + 1;
    for (int kt = 0; kt < ntiles; ++kt) {
        __syncthreads();
        {
            const ushort_t* kp = ksrc + (size_t)kt * 64 * 2304;
            *(uint4*)KsW       = *(const uint4*)kp;
            *(uint4*)(KsW + 8) = *(const uint4*)(kp + 8);
            const ushort_t* vp = vsrc + kt * 64;
            *(uint4*)VtW       = *(const uint4*)vp;
            *(uint4*)(VtW + 8) = *(const uint4*)(vp + 8);
        }
        __syncthreads();

        // S = Q K^T  (raw, scale folded into exp)
        f32x4 sf[4];
        #pragma unroll
        for (int nk = 0; nk < 4; ++nk) {
            bf16x8 kf0 = *(const bf16x8*)&Ks[nk * 16 + c][g * 8];
            bf16x8 kf1 = *(const bf16x8*)&Ks[nk * 16 + c][g * 8 + 32];
            f32x4 z = {};
            z = __builtin_amdgcn_mfma_f32_16x16x32_bf16(qa0, kf0, z, 0, 0, 0);
            z = __builtin_amdgcn_mfma_f32_16x16x32_bf16(qa1, kf1, z, 0, 0, 0);
            sf[nk] = z;
        }
        // causal mask + row max
        float pmax[4] = {-1e30f, -1e30f, -1e30f, -1e30f};
        #pragma unroll
        for (int nk = 0; nk < 4; ++nk) {
            int key = kt * 64 + nk * 16 + c;
            #pragma unroll
            for (int q = 0; q < 4; ++q) {
                float sv = sf[nk][q];
                int row = qrow0 + g * 4 + q;
                sv = (key > row) ? -1e30f : sv;
                sf[nk][q] = sv;
                pmax[q] = fmaxf(pmax[q], sv);
            }
        }
        #pragma unroll
        for (int q = 0; q < 4; ++q)
            #pragma unroll
            for (int off = 1; off < 16; off <<= 1)
                pmax[q] = fmaxf(pmax[q], __shfl_xor(pmax[q], off));
        float corr[4], psum[4];
        #pragma unroll
        for (int q = 0; q < 4; ++q) {
            float mn = fmaxf(mrun[q], pmax[q]);
            corr[q] = __expf((mrun[q] - mn) * 0.125f);
            mrun[q] = mn;
            psum[q] = 0.0f;
        }
        #pragma unroll
        for (int nk = 0; nk < 4; ++nk)
            #pragma unroll
            for (int q = 0; q < 4; ++q) {
                float p = __expf((sf[nk][q] - mrun[q]) * 0.125f);
                psum[q] += p;
                Pl[w][g * 4 + q][nk * 16 + c] = f2bf(p);
            }
        #pragma unroll
        for (int q = 0; q < 4; ++q) {
            #pragma unroll
            for (int off = 1; off < 16; off <<= 1)
                psum[q] += __shfl_xor(psum[q], off);
            lrun[q] = lrun[q] * corr[q] + psum[q];
        }
        #pragma unroll
        for (int ni = 0; ni < 4; ++ni)
            #pragma unroll
            for (int q = 0; q < 4; ++q)
                accO[ni][q] *= corr[q];

        asm volatile("" ::: "memory");   // keep P writes before P reads
        // O += P V
        bf16x8 pa0 = *(const bf16x8*)&Pl[w][c][g * 8];
        bf16x8 pa1 = *(const bf16x8*)&Pl[w][c][g * 8 + 32];
        #pragma unroll
        for (int ni = 0; ni < 4; ++ni) {
            bf16x8 bv0 = *(const bf16x8*)&Vt[ni * 16 + c][g * 8];
            bf16x8 bv1 = *(const bf16x8*)&Vt[ni * 16 + c][g * 8 + 32];
            accO[ni] = __builtin_amdgcn_mfma_f32_16x16x32_bf16(pa0, bv0, accO[ni], 0, 0, 0);
            accO[ni] = __builtin_amdgcn_mfma_f32_16x16x32_bf16(pa1, bv1, accO[ni], 0, 0, 0);
        }
    }

    #pragma unroll
    for (int q = 0; q < 4; ++q) {
        float inv = 1.0f / lrun[q];
        ushort_t* yr = yb + (size_t)(b * Tn + qrow0 + g * 4 + q) * Cdim + h * 64;
        #pragma unroll
        for (int ni = 0; ni < 4; ++ni)
            yr[ni * 16 + c] = f2bf(accO[ni][q] * inv);
    }
}

extern "C" void kernel_launch(void* const* d_in, const int* in_sizes, int n_in,
                              void* d_out, int out_size, void* d_ws, size_t ws_size,
                              hipStream_t stream) {
    const int*   idx  = (const int*)d_in[0];
    const float* wte  = (const float*)d_in[1];
    const float* wpe  = (const float*)d_in[2];
    const float* ln1w = (const float*)d_in[3];
    const float* ln1b = (const float*)d_in[4];
    const float* Wq   = (const float*)d_in[5];
    const float* bq   = (const float*)d_in[6];
    const float* Wk   = (const float*)d_in[7];
    const float* bk   = (const float*)d_in[8];
    const float* Wv   = (const float*)d_in[9];
    const float* bv   = (const float*)d_in[10];
    const float* Wo   = (const float*)d_in[11];
    const float* bo   = (const float*)d_in[12];
    const float* ln2w = (const float*)d_in[13];
    const float* ln2b = (const float*)d_in[14];
    const float* Wfc  = (const float*)d_in[15];
    const float* bfc  = (const float*)d_in[16];
    const float* Wpr  = (const float*)d_in[17];
    const float* bpr  = (const float*)d_in[18];
    const float* lnfw = (const float*)d_in[19];
    const float* lnfb = (const float*)d_in[20];
    const float* Wlm  = (const float*)d_in[21];
    float* out = (float*)d_out;

    const int M = Mrows;                      // 2048
    const int V = out_size / M;               // 50257
    const int Vpad = ((V + 127) / 128) * 128; // 50304

    float*    x     = (float*)d_ws;
    float*    bqkv  = x + (size_t)M * Cdim;
    ushort_t* qkvb  = (ushort_t*)(bqkv + 2304);
    ushort_t* vtb   = qkvb + (size_t)M * 2304;           // 24*64*1024
    ushort_t* hb    = vtb + (size_t)Bn * Hn * 64 * Tn;
    ushort_t* yb    = hb + (size_t)M * Cdim;
    ushort_t* mid   = yb + (size_t)M * Cdim;             // M*3072
    ushort_t* wqkvt = mid + (size_t)M * 3072;
    ushort_t* wot   = wqkvt + (size_t)2304 * Cdim;
    ushort_t* wfct  = wot + (size_t)Cdim * Cdim;
    ushort_t* wprt  = wfct + (size_t)3072 * Cdim;
    ushort_t* wlmt  = wprt + (size_t)Cdim * 3072;

    embed_k<<<(M * Cdim) / 256, 256, 0, stream>>>(idx, wte, wpe, x);

    for (int l = 0; l < Ln; ++l) {
        const size_t wo2 = (size_t)l * Cdim * Cdim;
        const size_t wo4 = (size_t)l * Cdim * 4 * Cdim;
        conv4_k<<<dim3(24, 24, 4), 256, 0, stream>>>(
            Wq + wo2, Wk + wo2, Wv + wo2, Wo + wo2, wqkvt, wot);
        conv2_k<<<dim3(2304, 1, 2), 256, 0, stream>>>(Wfc + wo4, Wpr + wo4, wfct, wprt);
        packb_k<<<9, 256, 0, stream>>>(bq + l * Cdim, bk + l * Cdim, bv + l * Cdim, bqkv);

        ln_k<<<M, 256, 0, stream>>>(x, ln1w + l * Cdim, ln1b + l * Cdim, hb);
        gemm_bf16_k<true, false, false, true><<<dim3(18, 16), 256, 0, stream>>>(
            hb, wqkvt, bqkv, nullptr, qkvb, M, 2304, Cdim);
        vtrans_k<<<dim3(4, Hn, Bn), 256, 0, stream>>>(qkvb, vtb);
        attn_mfma_k<<<dim3(16, Hn, Bn), 256, 0, stream>>>(qkvb, vtb, yb);
        gemm_bf16_k<true, false, true, false><<<dim3(6, 16), 256, 0, stream>>>(
            yb, wot, bo + l * Cdim, x, x, M, Cdim, Cdim);
        ln_k<<<M, 256, 0, stream>>>(x, ln2w + l * Cdim, ln2b + l * Cdim, hb);
        gemm_bf16_k<true, true, false, true><<<dim3(24, 16), 256, 0, stream>>>(
            hb, wfct, bfc + (size_t)l * 4 * Cdim, nullptr, mid, M, 3072, Cdim);
        gemm_bf16_k<true, false, true, false><<<dim3(6, 16), 256, 0, stream>>>(
            mid, wprt, bpr + l * Cdim, x, x, M, Cdim, 3072);
    }

    ln_k<<<M, 256, 0, stream>>>(x, lnfw, lnfb, hb);
    wconv_k<<<dim3(Vpad / 32, 24), 256, 0, stream>>>(Wlm, wlmt, Cdim, V);
    gemm_bf16_k<false, false, false, false><<<dim3(Vpad / 128, 16), 256, 0, stream>>>(
        hb, wlmt, nullptr, nullptr, out, M, V, Cdim);
}

// Round 4
// 2402.820 us; speedup vs baseline: 8.8856x; 1.2383x over previous
//
#include <hip/hip_runtime.h>
#include <math.h>
#include <cstddef>

// GPT-2 small forward: L=12 H=12 C=768 D=64 V=50257, B=2 T=1024 (M=2048)
// Round 4: LM-head grid swap (M-tile fastest -> Wlm streamed once, B-strip
// L2-hot), 64x64-tile GEMM for N=768 layers (384 blocks vs 96), merged
// per-layer weight-conv+bias-pack kernel.

#define Cdim 768
#define Hn   12
#define Ln   12
#define Tn   1024
#define Bn   2
#define Mrows (Bn * Tn)

typedef unsigned short ushort_t;
typedef __bf16 bf16x8 __attribute__((ext_vector_type(8)));
typedef float  f32x4  __attribute__((ext_vector_type(4)));

__device__ __forceinline__ ushort_t f2bf(float v) {
    union { float f; unsigned int u; } x; x.f = v;
    unsigned int r = x.u + 0x7fffu + ((x.u >> 16) & 1u);   // RNE
    return (ushort_t)(r >> 16);
}
__device__ __forceinline__ float gelu_f(float v) {
    return 0.5f * v * (1.0f + erff(v * 0.70710678118654752f));
}
__device__ __forceinline__ void gload16(const void* g, void* l) {
    __builtin_amdgcn_global_load_lds(
        (const __attribute__((address_space(1))) unsigned int*)g,
        (__attribute__((address_space(3))) unsigned int*)l, 16, 0, 0);
}

// ---------------- embedding ----------------
__global__ void embed_k(const int* __restrict__ idx, const float* __restrict__ wte,
                        const float* __restrict__ wpe, float* __restrict__ x) {
    int i = blockIdx.x * 256 + threadIdx.x;
    int c  = i % Cdim;
    int bt = i / Cdim;
    int t  = bt % Tn;
    int tok = idx[bt];
    x[i] = wte[(size_t)tok * Cdim + c] + wpe[(size_t)t * Cdim + c];
}

// ---------------- layer norm -> bf16 ----------------
__global__ __launch_bounds__(256) void ln_k(const float* __restrict__ x,
                                            const float* __restrict__ w,
                                            const float* __restrict__ b,
                                            ushort_t* __restrict__ out) {
    int row = blockIdx.x;
    const float* xr = x + (size_t)row * Cdim;
    int t = threadIdx.x;
    float v0 = xr[t], v1 = xr[t + 256], v2 = xr[t + 512];
    float s = v0 + v1 + v2;
    #pragma unroll
    for (int o = 32; o > 0; o >>= 1) s += __shfl_xor(s, o);
    __shared__ float red[8];
    int wid = t >> 6;
    if ((t & 63) == 0) red[wid] = s;
    __syncthreads();
    float mean = (red[0] + red[1] + red[2] + red[3]) * (1.0f / 768.0f);
    float d0 = v0 - mean, d1 = v1 - mean, d2 = v2 - mean;
    float sq = d0 * d0 + d1 * d1 + d2 * d2;
    #pragma unroll
    for (int o = 32; o > 0; o >>= 1) sq += __shfl_xor(sq, o);
    if ((t & 63) == 0) red[4 + wid] = sq;
    __syncthreads();
    float var = (red[4] + red[5] + red[6] + red[7]) * (1.0f / 768.0f);
    float rstd = rsqrtf(var + 1e-5f);
    ushort_t* orow = out + (size_t)row * Cdim;
    orow[t]       = f2bf(d0 * rstd * w[t]       + b[t]);
    orow[t + 256] = f2bf(d1 * rstd * w[t + 256] + b[t + 256]);
    orow[t + 512] = f2bf(d2 * rstd * w[t + 512] + b[t + 512]);
}

// ---------------- 32x32 transpose+cast tile helper ----------------
__device__ __forceinline__ void tconv_tile(const float* __restrict__ W,
                                           ushort_t* __restrict__ WT,
                                           int K, int N, int n0, int k0, bool guard) {
    __shared__ float t[32][33];
    int x = threadIdx.x & 31, y = threadIdx.x >> 5;
    #pragma unroll
    for (int j = 0; j < 4; ++j) {
        int kk = k0 + y + j * 8, nn = n0 + x;
        t[y + j * 8][x] = (!guard || nn < N) ? W[(size_t)kk * N + nn] : 0.0f;
    }
    __syncthreads();
    #pragma unroll
    for (int j = 0; j < 4; ++j) {
        int nn = n0 + y + j * 8, kk = k0 + x;
        WT[(size_t)nn * K + kk] = f2bf(t[x][y + j * 8]);
    }
}

// LM head conversion (N guard / zero-pad)
__global__ __launch_bounds__(256) void wconv_k(const float* __restrict__ W,
                                               ushort_t* __restrict__ WT,
                                               int K, int N) {
    tconv_tile(W, WT, K, N, blockIdx.x * 32, blockIdx.y * 32, true);
}

// ---- one launch per layer: q,k,v,o (4x 768x768) + fc + pr + bias pack ----
// flat grid: 2304 (qkvo) + 2304 (fc) + 2304 (pr) + 9 (bias) = 6921
__global__ __launch_bounds__(256) void conv_layer_k(
    const float* __restrict__ Wq, const float* __restrict__ Wk,
    const float* __restrict__ Wv, const float* __restrict__ Wo,
    const float* __restrict__ Wfc, const float* __restrict__ Wpr,
    const float* __restrict__ bq, const float* __restrict__ bk,
    const float* __restrict__ bv,
    ushort_t* __restrict__ wqkvt, ushort_t* __restrict__ wot,
    ushort_t* __restrict__ wfct,  ushort_t* __restrict__ wprt,
    float* __restrict__ bqkv) {
    int bid = blockIdx.x;
    if (bid < 2304) {
        int z = bid / 576, t = bid % 576;
        const float* W = (z == 0) ? Wq : (z == 1) ? Wk : (z == 2) ? Wv : Wo;
        ushort_t* dst = (z < 3) ? (wqkvt + (size_t)z * 768 * 768) : wot;
        tconv_tile(W, dst, 768, 768, (t % 24) * 32, (t / 24) * 32, false);
    } else if (bid < 4608) {
        int t = bid - 2304;
        tconv_tile(Wfc, wfct, 768, 3072, (t % 96) * 32, (t / 96) * 32, false);
    } else if (bid < 6912) {
        int t = bid - 4608;
        tconv_tile(Wpr, wprt, 3072, 768, (t % 24) * 32, (t / 24) * 32, false);
    } else {
        int i = (bid - 6912) * 256 + threadIdx.x;   // 0..2303
        bqkv[i] = (i < 768) ? bq[i] : (i < 1536 ? bk[i - 768] : bv[i - 1536]);
    }
}

// ---------------- bf16 MFMA GEMM, 128x128 tile (m97 structure) ----------------
// SWAP: blockIdx.x indexes M (fastest) -> consecutive blocks share the B strip.
template <bool BIAS, bool GELU_, bool RES, bool OUTBF16, bool SWAP>
__global__ __launch_bounds__(256) void gemm_bf16_k(
    const ushort_t* __restrict__ A, const ushort_t* __restrict__ Bt,
    const float* __restrict__ bias, const float* __restrict__ res,
    void* __restrict__ Cout, int M, int N, int K) {
    __shared__ ushort_t Alds[128 * 32];
    __shared__ ushort_t Blds[128 * 32];
    const int tid = threadIdx.x;
    const int lane = tid & 63;
    const int w = tid >> 6;
    const int wr = w >> 1, wc = w & 1;
    const int m0 = (SWAP ? blockIdx.x : blockIdx.y) * 128;
    const int n0 = (SWAP ? blockIdx.y : blockIdx.x) * 128;

    f32x4 acc[4][4] = {};
    const int srow = w * 32 + (lane >> 2);
    const int skoff = (lane & 3) * 8;
    const ushort_t* Ab = A  + (size_t)(m0 + srow) * K + skoff;
    const ushort_t* Bb = Bt + (size_t)(n0 + srow) * K + skoff;
    char* Al = (char*)Alds + (w * 2048 + lane * 16);
    char* Bl = (char*)Blds + (w * 2048 + lane * 16);

    const int nk = K >> 5;
    for (int kb = 0; kb < nk; ++kb) {
        const int k0 = kb << 5;
        __syncthreads();
        gload16(Ab + k0,                  Al);
        gload16(Ab + k0 + (size_t)16 * K, Al + 1024);
        gload16(Bb + k0,                  Bl);
        gload16(Bb + k0 + (size_t)16 * K, Bl + 1024);
        __syncthreads();
        bf16x8 af[4], bfr[4];
        #pragma unroll
        for (int i = 0; i < 4; ++i) {
            af[i]  = *(const bf16x8*)((const char*)Alds +
                       ((wr * 64 + i * 16 + (lane & 15)) * 64 + (lane >> 4) * 16));
            bfr[i] = *(const bf16x8*)((const char*)Blds +
                       ((wc * 64 + i * 16 + (lane & 15)) * 64 + (lane >> 4) * 16));
        }
        #pragma unroll
        for (int mi = 0; mi < 4; ++mi)
            #pragma unroll
            for (int ni = 0; ni < 4; ++ni)
                acc[mi][ni] = __builtin_amdgcn_mfma_f32_16x16x32_bf16(
                    af[mi], bfr[ni], acc[mi][ni], 0, 0, 0);
    }
    const int r0 = (lane >> 4) * 4;
    const int c0 = lane & 15;
    #pragma unroll
    for (int mi = 0; mi < 4; ++mi) {
        #pragma unroll
        for (int ni = 0; ni < 4; ++ni) {
            int col = n0 + wc * 64 + ni * 16 + c0;
            if (col < N) {
                #pragma unroll
                for (int q = 0; q < 4; ++q) {
                    int row = m0 + wr * 64 + mi * 16 + r0 + q;
                    float v = acc[mi][ni][q];
                    if (BIAS) v += bias[col];
                    if (GELU_) v = gelu_f(v);
                    if (RES) v += res[(size_t)row * N + col];
                    if (OUTBF16) ((ushort_t*)Cout)[(size_t)row * N + col] = f2bf(v);
                    else         ((float*)Cout)[(size_t)row * N + col] = v;
                }
            }
        }
    }
}

// ---------------- bf16 MFMA GEMM, 64x64 tile (for small-N latency-bound) ----
// 4 waves 2x2, each wave 32x32 out; 1 gload per operand per K-step.
template <bool BIAS, bool RES>
__global__ __launch_bounds__(256) void gemm64_k(
    const ushort_t* __restrict__ A, const ushort_t* __restrict__ Bt,
    const float* __restrict__ bias, const float* __restrict__ res,
    float* __restrict__ Cout, int M, int N, int K) {
    __shared__ ushort_t Alds[64 * 32];
    __shared__ ushort_t Blds[64 * 32];
    const int tid = threadIdx.x;
    const int lane = tid & 63;
    const int w = tid >> 6;
    const int wr = w >> 1, wc = w & 1;
    const int m0 = blockIdx.y * 64;
    const int n0 = blockIdx.x * 64;

    f32x4 acc[2][2] = {};
    const int srow = w * 16 + (lane >> 2);
    const int skoff = (lane & 3) * 8;
    const ushort_t* Ab = A  + (size_t)(m0 + srow) * K + skoff;
    const ushort_t* Bb = Bt + (size_t)(n0 + srow) * K + skoff;
    char* Al = (char*)Alds + (w * 1024 + lane * 16);
    char* Bl = (char*)Blds + (w * 1024 + lane * 16);

    const int nk = K >> 5;
    for (int kb = 0; kb < nk; ++kb) {
        const int k0 = kb << 5;
        __syncthreads();
        gload16(Ab + k0, Al);
        gload16(Bb + k0, Bl);
        __syncthreads();
        bf16x8 af[2], bfr[2];
        #pragma unroll
        for (int i = 0; i < 2; ++i) {
            af[i]  = *(const bf16x8*)((const char*)Alds +
                       ((wr * 32 + i * 16 + (lane & 15)) * 64 + (lane >> 4) * 16));
            bfr[i] = *(const bf16x8*)((const char*)Blds +
                       ((wc * 32 + i * 16 + (lane & 15)) * 64 + (lane >> 4) * 16));
        }
        #pragma unroll
        for (int mi = 0; mi < 2; ++mi)
            #pragma unroll
            for (int ni = 0; ni < 2; ++ni)
                acc[mi][ni] = __builtin_amdgcn_mfma_f32_16x16x32_bf16(
                    af[mi], bfr[ni], acc[mi][ni], 0, 0, 0);
    }
    const int r0 = (lane >> 4) * 4;
    const int c0 = lane & 15;
    #pragma unroll
    for (int mi = 0; mi < 2; ++mi)
        #pragma unroll
        for (int ni = 0; ni < 2; ++ni) {
            int col = n0 + wc * 32 + ni * 16 + c0;
            #pragma unroll
            for (int q = 0; q < 4; ++q) {
                int row = m0 + wr * 32 + mi * 16 + r0 + q;
                float v = acc[mi][ni][q];
                if (BIAS) v += bias[col];
                if (RES) v += res[(size_t)row * N + col];
                Cout[(size_t)row * N + col] = v;
            }
        }
}

// ---------------- per-layer V transpose ----------------
__global__ __launch_bounds__(256) void vtrans_k(const ushort_t* __restrict__ qkvb,
                                                ushort_t* __restrict__ vtb) {
    __shared__ ushort_t Ls[256][72];
    const int tc = blockIdx.x, h = blockIdx.y, b = blockIdx.z;
    const int tid = threadIdx.x;
    const ushort_t* src = qkvb + (size_t)(b * Tn + tc * 256 + tid) * 2304 + 1536 + h * 64;
    #pragma unroll
    for (int i = 0; i < 8; ++i)
        *(uint4*)&Ls[tid][i * 8] = *(const uint4*)(src + i * 8);
    __syncthreads();
    const int d = tid & 63, tg = tid >> 6;
    ushort_t tmp[64];
    #pragma unroll
    for (int i = 0; i < 64; ++i) tmp[i] = Ls[tg * 64 + i][d];
    ushort_t* dst = vtb + ((size_t)(b * Hn + h) * 64 + d) * Tn + tc * 256 + tg * 64;
    #pragma unroll
    for (int i = 0; i < 8; ++i)
        *(uint4*)&dst[i * 8] = *(const uint4*)&tmp[i * 8];
}

// ---------------- MFMA flash attention ----------------
__global__ __launch_bounds__(256) void attn_mfma_k(
    const ushort_t* __restrict__ qkvb,
    const ushort_t* __restrict__ vtb,
    ushort_t* __restrict__ yb) {
    __shared__ ushort_t Ks[64][72];
    __shared__ ushort_t Vt[64][72];
    __shared__ ushort_t Pl[4][16][72];
    const int chunk = (Tn / 64 - 1) - blockIdx.x;
    const int h = blockIdx.y, b = blockIdx.z;
    const int tid = threadIdx.x, lane = tid & 63, w = tid >> 6;
    const int c = lane & 15, g = lane >> 4;
    const int qrow0 = chunk * 64 + w * 16;

    const ushort_t* qp = qkvb + (size_t)(b * Tn + qrow0 + c) * 2304 + h * 64 + g * 8;
    bf16x8 qa0 = *(const bf16x8*)qp;
    bf16x8 qa1 = *(const bf16x8*)(qp + 32);

    f32x4 accO[4] = {};
    float mrun[4], lrun[4];
    #pragma unroll
    for (int q = 0; q < 4; ++q) { mrun[q] = -1e30f; lrun[q] = 0.0f; }

    const int skey = tid >> 2, sd0 = (tid & 3) * 16;
    const ushort_t* ksrc = qkvb + (size_t)(b * Tn + skey) * 2304 + 768 + h * 64 + sd0;
    const int vd = tid >> 2, vseg = tid & 3;
    const ushort_t* vsrc = vtb + ((size_t)(b * Hn + h) * 64 + vd) * Tn + vseg * 16;
    ushort_t* KsW = &Ks[skey][sd0];
    ushort_t* VtW = &Vt[vd][vseg * 16];

    const int ntiles = chunk + 1;
    for (int kt = 0; kt < ntiles; ++kt) {
        __syncthreads();
        {
            const ushort_t* kp = ksrc + (size_t)kt * 64 * 2304;
            *(uint4*)KsW       = *(const uint4*)kp;
            *(uint4*)(KsW + 8) = *(const uint4*)(kp + 8);
            const ushort_t* vp = vsrc + kt * 64;
            *(uint4*)VtW       = *(const uint4*)vp;
            *(uint4*)(VtW + 8) = *(const uint4*)(vp + 8);
        }
        __syncthreads();

        f32x4 sf[4];
        #pragma unroll
        for (int nk = 0; nk < 4; ++nk) {
            bf16x8 kf0 = *(const bf16x8*)&Ks[nk * 16 + c][g * 8];
            bf16x8 kf1 = *(const bf16x8*)&Ks[nk * 16 + c][g * 8 + 32];
            f32x4 z = {};
            z = __builtin_amdgcn_mfma_f32_16x16x32_bf16(qa0, kf0, z, 0, 0, 0);
            z = __builtin_amdgcn_mfma_f32_16x16x32_bf16(qa1, kf1, z, 0, 0, 0);
            sf[nk] = z;
        }
        float pmax[4] = {-1e30f, -1e30f, -1e30f, -1e30f};
        #pragma unroll
        for (int nk = 0; nk < 4; ++nk) {
            int key = kt * 64 + nk * 16 + c;
            #pragma unroll
            for (int q = 0; q < 4; ++q) {
                float sv = sf[nk][q];
                int row = qrow0 + g * 4 + q;
                sv = (key > row) ? -1e30f : sv;
                sf[nk][q] = sv;
                pmax[q] = fmaxf(pmax[q], sv);
            }
        }
        #pragma unroll
        for (int q = 0; q < 4; ++q)
            #pragma unroll
            for (int off = 1; off < 16; off <<= 1)
                pmax[q] = fmaxf(pmax[q], __shfl_xor(pmax[q], off));
        float corr[4], psum[4];
        #pragma unroll
        for (int q = 0; q < 4; ++q) {
            float mn = fmaxf(mrun[q], pmax[q]);
            corr[q] = __expf((mrun[q] - mn) * 0.125f);
            mrun[q] = mn;
            psum[q] = 0.0f;
        }
        #pragma unroll
        for (int nk = 0; nk < 4; ++nk)
            #pragma unroll
            for (int q = 0; q < 4; ++q) {
                float p = __expf((sf[nk][q] - mrun[q]) * 0.125f);
                psum[q] += p;
                Pl[w][g * 4 + q][nk * 16 + c] = f2bf(p);
            }
        #pragma unroll
        for (int q = 0; q < 4; ++q) {
            #pragma unroll
            for (int off = 1; off < 16; off <<= 1)
                psum[q] += __shfl_xor(psum[q], off);
            lrun[q] = lrun[q] * corr[q] + psum[q];
        }
        #pragma unroll
        for (int ni = 0; ni < 4; ++ni)
            #pragma unroll
            for (int q = 0; q < 4; ++q)
                accO[ni][q] *= corr[q];

        asm volatile("" ::: "memory");
        bf16x8 pa0 = *(const bf16x8*)&Pl[w][c][g * 8];
        bf16x8 pa1 = *(const bf16x8*)&Pl[w][c][g * 8 + 32];
        #pragma unroll
        for (int ni = 0; ni < 4; ++ni) {
            bf16x8 bv0 = *(const bf16x8*)&Vt[ni * 16 + c][g * 8];
            bf16x8 bv1 = *(const bf16x8*)&Vt[ni * 16 + c][g * 8 + 32];
            accO[ni] = __builtin_amdgcn_mfma_f32_16x16x32_bf16(pa0, bv0, accO[ni], 0, 0, 0);
            accO[ni] = __builtin_amdgcn_mfma_f32_16x16x32_bf16(pa1, bv1, accO[ni], 0, 0, 0);
        }
    }

    #pragma unroll
    for (int q = 0; q < 4; ++q) {
        float inv = 1.0f / lrun[q];
        ushort_t* yr = yb + (size_t)(b * Tn + qrow0 + g * 4 + q) * Cdim + h * 64;
        #pragma unroll
        for (int ni = 0; ni < 4; ++ni)
            yr[ni * 16 + c] = f2bf(accO[ni][q] * inv);
    }
}

extern "C" void kernel_launch(void* const* d_in, const int* in_sizes, int n_in,
                              void* d_out, int out_size, void* d_ws, size_t ws_size,
                              hipStream_t stream) {
    const int*   idx  = (const int*)d_in[0];
    const float* wte  = (const float*)d_in[1];
    const float* wpe  = (const float*)d_in[2];
    const float* ln1w = (const float*)d_in[3];
    const float* ln1b = (const float*)d_in[4];
    const float* Wq   = (const float*)d_in[5];
    const float* bq   = (const float*)d_in[6];
    const float* Wk   = (const float*)d_in[7];
    const float* bk   = (const float*)d_in[8];
    const float* Wv   = (const float*)d_in[9];
    const float* bv   = (const float*)d_in[10];
    const float* Wo   = (const float*)d_in[11];
    const float* bo   = (const float*)d_in[12];
    const float* ln2w = (const float*)d_in[13];
    const float* ln2b = (const float*)d_in[14];
    const float* Wfc  = (const float*)d_in[15];
    const float* bfc  = (const float*)d_in[16];
    const float* Wpr  = (const float*)d_in[17];
    const float* bpr  = (const float*)d_in[18];
    const float* lnfw = (const float*)d_in[19];
    const float* lnfb = (const float*)d_in[20];
    const float* Wlm  = (const float*)d_in[21];
    float* out = (float*)d_out;

    const int M = Mrows;                      // 2048
    const int V = out_size / M;               // 50257
    const int Vpad = ((V + 127) / 128) * 128; // 50304

    float*    x     = (float*)d_ws;
    float*    bqkv  = x + (size_t)M * Cdim;
    ushort_t* qkvb  = (ushort_t*)(bqkv + 2304);
    ushort_t* vtb   = qkvb + (size_t)M * 2304;
    ushort_t* hb    = vtb + (size_t)Bn * Hn * 64 * Tn;
    ushort_t* yb    = hb + (size_t)M * Cdim;
    ushort_t* mid   = yb + (size_t)M * Cdim;
    ushort_t* wqkvt = mid + (size_t)M * 3072;
    ushort_t* wot   = wqkvt + (size_t)2304 * Cdim;
    ushort_t* wfct  = wot + (size_t)Cdim * Cdim;
    ushort_t* wprt  = wfct + (size_t)3072 * Cdim;
    ushort_t* wlmt  = wprt + (size_t)Cdim * 3072;

    embed_k<<<(M * Cdim) / 256, 256, 0, stream>>>(idx, wte, wpe, x);

    for (int l = 0; l < Ln; ++l) {
        const size_t wo2 = (size_t)l * Cdim * Cdim;
        const size_t wo4 = (size_t)l * Cdim * 4 * Cdim;
        conv_layer_k<<<6921, 256, 0, stream>>>(
            Wq + wo2, Wk + wo2, Wv + wo2, Wo + wo2, Wfc + wo4, Wpr + wo4,
            bq + l * Cdim, bk + l * Cdim, bv + l * Cdim,
            wqkvt, wot, wfct, wprt, bqkv);

        ln_k<<<M, 256, 0, stream>>>(x, ln1w + l * Cdim, ln1b + l * Cdim, hb);
        gemm_bf16_k<true, false, false, true, false><<<dim3(18, 16), 256, 0, stream>>>(
            hb, wqkvt, bqkv, nullptr, qkvb, M, 2304, Cdim);
        vtrans_k<<<dim3(4, Hn, Bn), 256, 0, stream>>>(qkvb, vtb);
        attn_mfma_k<<<dim3(16, Hn, Bn), 256, 0, stream>>>(qkvb, vtb, yb);
        gemm64_k<true, true><<<dim3(12, 32), 256, 0, stream>>>(
            yb, wot, bo + l * Cdim, x, x, M, Cdim, Cdim);
        ln_k<<<M, 256, 0, stream>>>(x, ln2w + l * Cdim, ln2b + l * Cdim, hb);
        gemm_bf16_k<true, true, false, true, false><<<dim3(24, 16), 256, 0, stream>>>(
            hb, wfct, bfc + (size_t)l * 4 * Cdim, nullptr, mid, M, 3072, Cdim);
        gemm64_k<true, true><<<dim3(12, 32), 256, 0, stream>>>(
            mid, wprt, bpr + l * Cdim, x, x, M, Cdim, 3072);
    }

    ln_k<<<M, 256, 0, stream>>>(x, lnfw, lnfb, hb);
    wconv_k<<<dim3(Vpad / 32, 24), 256, 0, stream>>>(Wlm, wlmt, Cdim, V);
    // SWAP=true: blockIdx.x = M-tile (fastest) so 16 consecutive blocks share
    // one 196 KB B-strip (L2-hot); Wlm streams from HBM exactly once.
    gemm_bf16_k<false, false, false, false, true><<<dim3(16, Vpad / 128), 256, 0, stream>>>(
        hb, wlmt, nullptr, nullptr, out, M, V, Cdim);
}

// Round 5
// 2169.863 us; speedup vs baseline: 9.8395x; 1.1074x over previous
//
#include <hip/hip_runtime.h>
#include <math.h>
#include <cstddef>

// GPT-2 small forward: L=12 H=12 C=768 D=64 V=50257, B=2 T=1024 (M=2048)
// Round 5: BK=64 (2x sub-tile) 128x128 GEMM, BK=128 (4x sub-tile) 64x64 GEMM
// -> 2-4x more MFMA per barrier-pair; LM-head XCD-strip affinity (T1, exact
// 6288=8*786); packed-K buffer for coalesced attention staging.

#define Cdim 768
#define Hn   12
#define Ln   12
#define Tn   1024
#define Bn   2
#define Mrows (Bn * Tn)

typedef unsigned short ushort_t;
typedef __bf16 bf16x8 __attribute__((ext_vector_type(8)));
typedef float  f32x4  __attribute__((ext_vector_type(4)));

__device__ __forceinline__ ushort_t f2bf(float v) {
    union { float f; unsigned int u; } x; x.f = v;
    unsigned int r = x.u + 0x7fffu + ((x.u >> 16) & 1u);   // RNE
    return (ushort_t)(r >> 16);
}
__device__ __forceinline__ float gelu_f(float v) {
    return 0.5f * v * (1.0f + erff(v * 0.70710678118654752f));
}
__device__ __forceinline__ void gload16(const void* g, void* l) {
    __builtin_amdgcn_global_load_lds(
        (const __attribute__((address_space(1))) unsigned int*)g,
        (__attribute__((address_space(3))) unsigned int*)l, 16, 0, 0);
}

// ---------------- embedding ----------------
__global__ void embed_k(const int* __restrict__ idx, const float* __restrict__ wte,
                        const float* __restrict__ wpe, float* __restrict__ x) {
    int i = blockIdx.x * 256 + threadIdx.x;
    int c  = i % Cdim;
    int bt = i / Cdim;
    int t  = bt % Tn;
    int tok = idx[bt];
    x[i] = wte[(size_t)tok * Cdim + c] + wpe[(size_t)t * Cdim + c];
}

// ---------------- layer norm -> bf16 ----------------
__global__ __launch_bounds__(256) void ln_k(const float* __restrict__ x,
                                            const float* __restrict__ w,
                                            const float* __restrict__ b,
                                            ushort_t* __restrict__ out) {
    int row = blockIdx.x;
    const float* xr = x + (size_t)row * Cdim;
    int t = threadIdx.x;
    float v0 = xr[t], v1 = xr[t + 256], v2 = xr[t + 512];
    float s = v0 + v1 + v2;
    #pragma unroll
    for (int o = 32; o > 0; o >>= 1) s += __shfl_xor(s, o);
    __shared__ float red[8];
    int wid = t >> 6;
    if ((t & 63) == 0) red[wid] = s;
    __syncthreads();
    float mean = (red[0] + red[1] + red[2] + red[3]) * (1.0f / 768.0f);
    float d0 = v0 - mean, d1 = v1 - mean, d2 = v2 - mean;
    float sq = d0 * d0 + d1 * d1 + d2 * d2;
    #pragma unroll
    for (int o = 32; o > 0; o >>= 1) sq += __shfl_xor(sq, o);
    if ((t & 63) == 0) red[4 + wid] = sq;
    __syncthreads();
    float var = (red[4] + red[5] + red[6] + red[7]) * (1.0f / 768.0f);
    float rstd = rsqrtf(var + 1e-5f);
    ushort_t* orow = out + (size_t)row * Cdim;
    orow[t]       = f2bf(d0 * rstd * w[t]       + b[t]);
    orow[t + 256] = f2bf(d1 * rstd * w[t + 256] + b[t + 256]);
    orow[t + 512] = f2bf(d2 * rstd * w[t + 512] + b[t + 512]);
}

// ---------------- 32x32 transpose+cast tile helper ----------------
__device__ __forceinline__ void tconv_tile(const float* __restrict__ W,
                                           ushort_t* __restrict__ WT,
                                           int K, int N, int n0, int k0, bool guard) {
    __shared__ float t[32][33];
    int x = threadIdx.x & 31, y = threadIdx.x >> 5;
    #pragma unroll
    for (int j = 0; j < 4; ++j) {
        int kk = k0 + y + j * 8, nn = n0 + x;
        t[y + j * 8][x] = (!guard || nn < N) ? W[(size_t)kk * N + nn] : 0.0f;
    }
    __syncthreads();
    #pragma unroll
    for (int j = 0; j < 4; ++j) {
        int nn = n0 + y + j * 8, kk = k0 + x;
        WT[(size_t)nn * K + kk] = f2bf(t[x][y + j * 8]);
    }
}

// LM head conversion (N guard / zero-pad)
__global__ __launch_bounds__(256) void wconv_k(const float* __restrict__ W,
                                               ushort_t* __restrict__ WT,
                                               int K, int N) {
    tconv_tile(W, WT, K, N, blockIdx.x * 32, blockIdx.y * 32, true);
}

// ---- one launch per layer: q,k,v,o (4x 768x768) + fc + pr + bias pack ----
__global__ __launch_bounds__(256) void conv_layer_k(
    const float* __restrict__ Wq, const float* __restrict__ Wk,
    const float* __restrict__ Wv, const float* __restrict__ Wo,
    const float* __restrict__ Wfc, const float* __restrict__ Wpr,
    const float* __restrict__ bq, const float* __restrict__ bk,
    const float* __restrict__ bv,
    ushort_t* __restrict__ wqkvt, ushort_t* __restrict__ wot,
    ushort_t* __restrict__ wfct,  ushort_t* __restrict__ wprt,
    float* __restrict__ bqkv) {
    int bid = blockIdx.x;
    if (bid < 2304) {
        int z = bid / 576, t = bid % 576;
        const float* W = (z == 0) ? Wq : (z == 1) ? Wk : (z == 2) ? Wv : Wo;
        ushort_t* dst = (z < 3) ? (wqkvt + (size_t)z * 768 * 768) : wot;
        tconv_tile(W, dst, 768, 768, (t % 24) * 32, (t / 24) * 32, false);
    } else if (bid < 4608) {
        int t = bid - 2304;
        tconv_tile(Wfc, wfct, 768, 3072, (t % 96) * 32, (t / 96) * 32, false);
    } else if (bid < 6912) {
        int t = bid - 4608;
        tconv_tile(Wpr, wprt, 3072, 768, (t % 24) * 32, (t / 24) * 32, false);
    } else {
        int i = (bid - 6912) * 256 + threadIdx.x;
        bqkv[i] = (i < 768) ? bq[i] : (i < 1536 ? bk[i - 768] : bv[i - 1536]);
    }
}

// -------- bf16 MFMA GEMM, 128x128 tile, BK=64 (2 sub-tiles per barrier) ------
// MODE 0: grid(x=N,y=M).  MODE 2: 1-D grid, T1 XCD-strip mapping (LM head);
// cpx = gridDim.x/8 (exact).
template <bool BIAS, bool GELU_, bool RES, bool OUTBF16, int MODE>
__global__ __launch_bounds__(256) void gemm_bf16_k(
    const ushort_t* __restrict__ A, const ushort_t* __restrict__ Bt,
    const float* __restrict__ bias, const float* __restrict__ res,
    void* __restrict__ Cout, int M, int N, int K, int cpx) {
    __shared__ ushort_t Alds[2][128 * 32];
    __shared__ ushort_t Blds[2][128 * 32];
    const int tid = threadIdx.x;
    const int lane = tid & 63;
    const int w = tid >> 6;
    const int wr = w >> 1, wc = w & 1;
    int m0, n0;
    if (MODE == 2) {
        int lid = (blockIdx.x & 7) * cpx + (blockIdx.x >> 3);
        m0 = (lid & 15) * 128;          // 16 M-tiles per N-strip
        n0 = (lid >> 4) * 128;
    } else {
        m0 = blockIdx.y * 128;
        n0 = blockIdx.x * 128;
    }

    f32x4 acc[4][4] = {};
    const int srow = w * 32 + (lane >> 2);
    const int skoff = (lane & 3) * 8;
    const ushort_t* Ab = A  + (size_t)(m0 + srow) * K + skoff;
    const ushort_t* Bb = Bt + (size_t)(n0 + srow) * K + skoff;
    char* Al0 = (char*)&Alds[0][0] + (w * 2048 + lane * 16);
    char* Al1 = (char*)&Alds[1][0] + (w * 2048 + lane * 16);
    char* Bl0 = (char*)&Blds[0][0] + (w * 2048 + lane * 16);
    char* Bl1 = (char*)&Blds[1][0] + (w * 2048 + lane * 16);

    const int nk = K >> 6;
    for (int kb = 0; kb < nk; ++kb) {
        const int k0 = kb << 6;
        __syncthreads();
        gload16(Ab + k0,                       Al0);
        gload16(Ab + k0 + (size_t)16 * K,      Al0 + 1024);
        gload16(Ab + k0 + 32,                  Al1);
        gload16(Ab + k0 + 32 + (size_t)16 * K, Al1 + 1024);
        gload16(Bb + k0,                       Bl0);
        gload16(Bb + k0 + (size_t)16 * K,      Bl0 + 1024);
        gload16(Bb + k0 + 32,                  Bl1);
        gload16(Bb + k0 + 32 + (size_t)16 * K, Bl1 + 1024);
        __syncthreads();
        #pragma unroll
        for (int h = 0; h < 2; ++h) {
            bf16x8 af[4], bfr[4];
            #pragma unroll
            for (int i = 0; i < 4; ++i) {
                af[i]  = *(const bf16x8*)((const char*)&Alds[h][0] +
                           ((wr * 64 + i * 16 + (lane & 15)) * 64 + (lane >> 4) * 16));
                bfr[i] = *(const bf16x8*)((const char*)&Blds[h][0] +
                           ((wc * 64 + i * 16 + (lane & 15)) * 64 + (lane >> 4) * 16));
            }
            #pragma unroll
            for (int mi = 0; mi < 4; ++mi)
                #pragma unroll
                for (int ni = 0; ni < 4; ++ni)
                    acc[mi][ni] = __builtin_amdgcn_mfma_f32_16x16x32_bf16(
                        af[mi], bfr[ni], acc[mi][ni], 0, 0, 0);
        }
    }
    const int r0 = (lane >> 4) * 4;
    const int c0 = lane & 15;
    #pragma unroll
    for (int mi = 0; mi < 4; ++mi) {
        #pragma unroll
        for (int ni = 0; ni < 4; ++ni) {
            int col = n0 + wc * 64 + ni * 16 + c0;
            if (col < N) {
                #pragma unroll
                for (int q = 0; q < 4; ++q) {
                    int row = m0 + wr * 64 + mi * 16 + r0 + q;
                    float v = acc[mi][ni][q];
                    if (BIAS) v += bias[col];
                    if (GELU_) v = gelu_f(v);
                    if (RES) v += res[(size_t)row * N + col];
                    if (OUTBF16) ((ushort_t*)Cout)[(size_t)row * N + col] = f2bf(v);
                    else         ((float*)Cout)[(size_t)row * N + col] = v;
                }
            }
        }
    }
}

// -------- bf16 MFMA GEMM, 64x64 tile, BK=128 (4 sub-tiles per barrier) -------
template <bool BIAS, bool RES>
__global__ __launch_bounds__(256) void gemm64_k(
    const ushort_t* __restrict__ A, const ushort_t* __restrict__ Bt,
    const float* __restrict__ bias, const float* __restrict__ res,
    float* __restrict__ Cout, int M, int N, int K) {
    __shared__ ushort_t Alds[4][64 * 32];
    __shared__ ushort_t Blds[4][64 * 32];
    const int tid = threadIdx.x;
    const int lane = tid & 63;
    const int w = tid >> 6;
    const int wr = w >> 1, wc = w & 1;
    const int m0 = blockIdx.y * 64;
    const int n0 = blockIdx.x * 64;

    f32x4 acc[2][2] = {};
    const int srow = w * 16 + (lane >> 2);
    const int skoff = (lane & 3) * 8;
    const ushort_t* Ab = A  + (size_t)(m0 + srow) * K + skoff;
    const ushort_t* Bb = Bt + (size_t)(n0 + srow) * K + skoff;

    const int nk = K >> 7;
    for (int kb = 0; kb < nk; ++kb) {
        const int k0 = kb << 7;
        __syncthreads();
        #pragma unroll
        for (int s = 0; s < 4; ++s) {
            gload16(Ab + k0 + s * 32, (char*)&Alds[s][0] + (w * 1024 + lane * 16));
            gload16(Bb + k0 + s * 32, (char*)&Blds[s][0] + (w * 1024 + lane * 16));
        }
        __syncthreads();
        #pragma unroll
        for (int s = 0; s < 4; ++s) {
            bf16x8 af[2], bfr[2];
            #pragma unroll
            for (int i = 0; i < 2; ++i) {
                af[i]  = *(const bf16x8*)((const char*)&Alds[s][0] +
                           ((wr * 32 + i * 16 + (lane & 15)) * 64 + (lane >> 4) * 16));
                bfr[i] = *(const bf16x8*)((const char*)&Blds[s][0] +
                           ((wc * 32 + i * 16 + (lane & 15)) * 64 + (lane >> 4) * 16));
            }
            #pragma unroll
            for (int mi = 0; mi < 2; ++mi)
                #pragma unroll
                for (int ni = 0; ni < 2; ++ni)
                    acc[mi][ni] = __builtin_amdgcn_mfma_f32_16x16x32_bf16(
                        af[mi], bfr[ni], acc[mi][ni], 0, 0, 0);
        }
    }
    const int r0 = (lane >> 4) * 4;
    const int c0 = lane & 15;
    #pragma unroll
    for (int mi = 0; mi < 2; ++mi)
        #pragma unroll
        for (int ni = 0; ni < 2; ++ni) {
            int col = n0 + wc * 32 + ni * 16 + c0;
            #pragma unroll
            for (int q = 0; q < 4; ++q) {
                int row = m0 + wr * 32 + mi * 16 + r0 + q;
                float v = acc[mi][ni][q];
                if (BIAS) v += bias[col];
                if (RES) v += res[(size_t)row * N + col];
                Cout[(size_t)row * N + col] = v;
            }
        }
}

// ------- per-layer K pack + V transpose: kpb[bh][T][64], vtb[bh][64][T] ------
__global__ __launch_bounds__(256) void kvprep_k(const ushort_t* __restrict__ qkvb,
                                                ushort_t* __restrict__ kpb,
                                                ushort_t* __restrict__ vtb) {
    __shared__ ushort_t Ls[256][72];
    const int tc = blockIdx.x, h = blockIdx.y, b = blockIdx.z;
    const int tid = threadIdx.x;
    const int tok = tc * 256 + tid;
    const ushort_t* base = qkvb + (size_t)(b * Tn + tok) * 2304 + h * 64;
    // K: straight packed copy (dest coalesced)
    ushort_t* kdst = kpb + ((size_t)(b * Hn + h) * Tn + tok) * 64;
    #pragma unroll
    for (int i = 0; i < 8; ++i)
        *(uint4*)&kdst[i * 8] = *(const uint4*)(base + 768 + i * 8);
    // V: transpose via LDS
    #pragma unroll
    for (int i = 0; i < 8; ++i)
        *(uint4*)&Ls[tid][i * 8] = *(const uint4*)(base + 1536 + i * 8);
    __syncthreads();
    const int d = tid & 63, tg = tid >> 6;
    ushort_t tmp[64];
    #pragma unroll
    for (int i = 0; i < 64; ++i) tmp[i] = Ls[tg * 64 + i][d];
    ushort_t* dst = vtb + ((size_t)(b * Hn + h) * 64 + d) * Tn + tc * 256 + tg * 64;
    #pragma unroll
    for (int i = 0; i < 8; ++i)
        *(uint4*)&dst[i * 8] = *(const uint4*)&tmp[i * 8];
}

// ---------------- MFMA flash attention ----------------
__global__ __launch_bounds__(256) void attn_mfma_k(
    const ushort_t* __restrict__ qkvb,
    const ushort_t* __restrict__ kpb,
    const ushort_t* __restrict__ vtb,
    ushort_t* __restrict__ yb) {
    __shared__ ushort_t Ks[64][72];
    __shared__ ushort_t Vt[64][72];
    __shared__ ushort_t Pl[4][16][72];
    const int chunk = (Tn / 64 - 1) - blockIdx.x;
    const int h = blockIdx.y, b = blockIdx.z;
    const int tid = threadIdx.x, lane = tid & 63, w = tid >> 6;
    const int c = lane & 15, g = lane >> 4;
    const int qrow0 = chunk * 64 + w * 16;

    const ushort_t* qp = qkvb + (size_t)(b * Tn + qrow0 + c) * 2304 + h * 64 + g * 8;
    bf16x8 qa0 = *(const bf16x8*)qp;
    bf16x8 qa1 = *(const bf16x8*)(qp + 32);

    f32x4 accO[4] = {};
    float mrun[4], lrun[4];
    #pragma unroll
    for (int q = 0; q < 4; ++q) { mrun[q] = -1e30f; lrun[q] = 0.0f; }

    const int skey = tid >> 2, sd0 = (tid & 3) * 16;
    const ushort_t* ksrc = kpb + ((size_t)(b * Hn + h) * Tn + skey) * 64 + sd0;
    const int vd = tid >> 2, vseg = tid & 3;
    const ushort_t* vsrc = vtb + ((size_t)(b * Hn + h) * 64 + vd) * Tn + vseg * 16;
    ushort_t* KsW = &Ks[skey][sd0];
    ushort_t* VtW = &Vt[vd][vseg * 16];

    const int ntiles = chunk + 1;
    for (int kt = 0; kt < ntiles; ++kt) {
        __syncthreads();
        {
            const ushort_t* kp = ksrc + (size_t)kt * 64 * 64;
            *(uint4*)KsW       = *(const uint4*)kp;
            *(uint4*)(KsW + 8) = *(const uint4*)(kp + 8);
            const ushort_t* vp = vsrc + kt * 64;
            *(uint4*)VtW       = *(const uint4*)vp;
            *(uint4*)(VtW + 8) = *(const uint4*)(vp + 8);
        }
        __syncthreads();

        f32x4 sf[4];
        #pragma unroll
        for (int nk = 0; nk < 4; ++nk) {
            bf16x8 kf0 = *(const bf16x8*)&Ks[nk * 16 + c][g * 8];
            bf16x8 kf1 = *(const bf16x8*)&Ks[nk * 16 + c][g * 8 + 32];
            f32x4 z = {};
            z = __builtin_amdgcn_mfma_f32_16x16x32_bf16(qa0, kf0, z, 0, 0, 0);
            z = __builtin_amdgcn_mfma_f32_16x16x32_bf16(qa1, kf1, z, 0, 0, 0);
            sf[nk] = z;
        }
        float pmax[4] = {-1e30f, -1e30f, -1e30f, -1e30f};
        #pragma unroll
        for (int nk = 0; nk < 4; ++nk) {
            int key = kt * 64 + nk * 16 + c;
            #pragma unroll
            for (int q = 0; q < 4; ++q) {
                float sv = sf[nk][q];
                int row = qrow0 + g * 4 + q;
                sv = (key > row) ? -1e30f : sv;
                sf[nk][q] = sv;
                pmax[q] = fmaxf(pmax[q], sv);
            }
        }
        #pragma unroll
        for (int q = 0; q < 4; ++q)
            #pragma unroll
            for (int off = 1; off < 16; off <<= 1)
                pmax[q] = fmaxf(pmax[q], __shfl_xor(pmax[q], off));
        float corr[4], psum[4];
        #pragma unroll
        for (int q = 0; q < 4; ++q) {
            float mn = fmaxf(mrun[q], pmax[q]);
            corr[q] = __expf((mrun[q] - mn) * 0.125f);
            mrun[q] = mn;
            psum[q] = 0.0f;
        }
        #pragma unroll
        for (int nk = 0; nk < 4; ++nk)
            #pragma unroll
            for (int q = 0; q < 4; ++q) {
                float p = __expf((sf[nk][q] - mrun[q]) * 0.125f);
                psum[q] += p;
                Pl[w][g * 4 + q][nk * 16 + c] = f2bf(p);
            }
        #pragma unroll
        for (int q = 0; q < 4; ++q) {
            #pragma unroll
            for (int off = 1; off < 16; off <<= 1)
                psum[q] += __shfl_xor(psum[q], off);
            lrun[q] = lrun[q] * corr[q] + psum[q];
        }
        #pragma unroll
        for (int ni = 0; ni < 4; ++ni)
            #pragma unroll
            for (int q = 0; q < 4; ++q)
                accO[ni][q] *= corr[q];

        asm volatile("" ::: "memory");
        bf16x8 pa0 = *(const bf16x8*)&Pl[w][c][g * 8];
        bf16x8 pa1 = *(const bf16x8*)&Pl[w][c][g * 8 + 32];
        #pragma unroll
        for (int ni = 0; ni < 4; ++ni) {
            bf16x8 bv0 = *(const bf16x8*)&Vt[ni * 16 + c][g * 8];
            bf16x8 bv1 = *(const bf16x8*)&Vt[ni * 16 + c][g * 8 + 32];
            accO[ni] = __builtin_amdgcn_mfma_f32_16x16x32_bf16(pa0, bv0, accO[ni], 0, 0, 0);
            accO[ni] = __builtin_amdgcn_mfma_f32_16x16x32_bf16(pa1, bv1, accO[ni], 0, 0, 0);
        }
    }

    #pragma unroll
    for (int q = 0; q < 4; ++q) {
        float inv = 1.0f / lrun[q];
        ushort_t* yr = yb + (size_t)(b * Tn + qrow0 + g * 4 + q) * Cdim + h * 64;
        #pragma unroll
        for (int ni = 0; ni < 4; ++ni)
            yr[ni * 16 + c] = f2bf(accO[ni][q] * inv);
    }
}

extern "C" void kernel_launch(void* const* d_in, const int* in_sizes, int n_in,
                              void* d_out, int out_size, void* d_ws, size_t ws_size,
                              hipStream_t stream) {
    const int*   idx  = (const int*)d_in[0];
    const float* wte  = (const float*)d_in[1];
    const float* wpe  = (const float*)d_in[2];
    const float* ln1w = (const float*)d_in[3];
    const float* ln1b = (const float*)d_in[4];
    const float* Wq   = (const float*)d_in[5];
    const float* bq   = (const float*)d_in[6];
    const float* Wk   = (const float*)d_in[7];
    const float* bk   = (const float*)d_in[8];
    const float* Wv   = (const float*)d_in[9];
    const float* bv   = (const float*)d_in[10];
    const float* Wo   = (const float*)d_in[11];
    const float* bo   = (const float*)d_in[12];
    const float* ln2w = (const float*)d_in[13];
    const float* ln2b = (const float*)d_in[14];
    const float* Wfc  = (const float*)d_in[15];
    const float* bfc  = (const float*)d_in[16];
    const float* Wpr  = (const float*)d_in[17];
    const float* bpr  = (const float*)d_in[18];
    const float* lnfw = (const float*)d_in[19];
    const float* lnfb = (const float*)d_in[20];
    const float* Wlm  = (const float*)d_in[21];
    float* out = (float*)d_out;

    const int M = Mrows;                      // 2048
    const int V = out_size / M;               // 50257
    const int Vpad = ((V + 127) / 128) * 128; // 50304

    float*    x     = (float*)d_ws;
    float*    bqkv  = x + (size_t)M * Cdim;
    ushort_t* qkvb  = (ushort_t*)(bqkv + 2304);
    ushort_t* kpb   = qkvb + (size_t)M * 2304;            // [B*H][Tn][64]
    ushort_t* vtb   = kpb + (size_t)Bn * Hn * Tn * 64;    // [B*H][64][Tn]
    ushort_t* hb    = vtb + (size_t)Bn * Hn * 64 * Tn;
    ushort_t* yb    = hb + (size_t)M * Cdim;
    ushort_t* mid   = yb + (size_t)M * Cdim;
    ushort_t* wqkvt = mid + (size_t)M * 3072;
    ushort_t* wot   = wqkvt + (size_t)2304 * Cdim;
    ushort_t* wfct  = wot + (size_t)Cdim * Cdim;
    ushort_t* wprt  = wfct + (size_t)3072 * Cdim;
    ushort_t* wlmt  = wprt + (size_t)Cdim * 3072;

    embed_k<<<(M * Cdim) / 256, 256, 0, stream>>>(idx, wte, wpe, x);

    for (int l = 0; l < Ln; ++l) {
        const size_t wo2 = (size_t)l * Cdim * Cdim;
        const size_t wo4 = (size_t)l * Cdim * 4 * Cdim;
        conv_layer_k<<<6921, 256, 0, stream>>>(
            Wq + wo2, Wk + wo2, Wv + wo2, Wo + wo2, Wfc + wo4, Wpr + wo4,
            bq + l * Cdim, bk + l * Cdim, bv + l * Cdim,
            wqkvt, wot, wfct, wprt, bqkv);

        ln_k<<<M, 256, 0, stream>>>(x, ln1w + l * Cdim, ln1b + l * Cdim, hb);
        gemm_bf16_k<true, false, false, true, 0><<<dim3(18, 16), 256, 0, stream>>>(
            hb, wqkvt, bqkv, nullptr, qkvb, M, 2304, Cdim, 0);
        kvprep_k<<<dim3(4, Hn, Bn), 256, 0, stream>>>(qkvb, kpb, vtb);
        attn_mfma_k<<<dim3(16, Hn, Bn), 256, 0, stream>>>(qkvb, kpb, vtb, yb);
        gemm64_k<true, true><<<dim3(12, 32), 256, 0, stream>>>(
            yb, wot, bo + l * Cdim, x, x, M, Cdim, Cdim);
        ln_k<<<M, 256, 0, stream>>>(x, ln2w + l * Cdim, ln2b + l * Cdim, hb);
        gemm_bf16_k<true, true, false, true, 0><<<dim3(24, 16), 256, 0, stream>>>(
            hb, wfct, bfc + (size_t)l * 4 * Cdim, nullptr, mid, M, 3072, Cdim, 0);
        gemm64_k<true, true><<<dim3(12, 32), 256, 0, stream>>>(
            mid, wprt, bpr + l * Cdim, x, x, M, Cdim, 3072);
    }

    ln_k<<<M, 256, 0, stream>>>(x, lnfw, lnfb, hb);
    wconv_k<<<dim3(Vpad / 32, 24), 256, 0, stream>>>(Wlm, wlmt, Cdim, V);
    // 1-D grid, T1 XCD-strip affinity: 6288 blocks = 8 XCDs x 786; each XCD
    // owns ~49 contiguous 128-col N-strips -> Wlm hits its L2 once.
    const int nblk = (Vpad / 128) * 16;       // 6288
    gemm_bf16_k<false, false, false, false, 2><<<nblk, 256, 0, stream>>>(
        hb, wlmt, nullptr, nullptr, out, M, V, Cdim, nblk / 8);
}